// Round 3
// baseline (959.525 us; speedup 1.0000x reference)
//
#include <hip/hip_runtime.h>
#include <hip/hip_bf16.h>
#include <math.h>

// ---------------- model dims ----------------
#define BB    8
#define TT    511
#define TC    512
#define DD    512
#define HH    8
#define HD    64
#define LL    4
#define FF    256
#define HEADH 32
#define NTOK  (BB*TC)      // 4096

typedef __bf16 bf16x8 __attribute__((ext_vector_type(8)));
typedef float  f32x4  __attribute__((ext_vector_type(4)));

__device__ __forceinline__ unsigned short f2b(float v) {
  __bf16 t = (__bf16)v;
  return __builtin_bit_cast(unsigned short, t);
}
__device__ __forceinline__ float gelu_f(float x) {
  return 0.5f * x * (1.0f + erff(x * 0.7071067811865476f));
}

// ---------------- fast wave reduce (64-lane): DPP + ds_swizzle + readlane ----------------
template<int CTRL>
__device__ __forceinline__ float dppmov(float x) {
  return __builtin_bit_cast(float,
      __builtin_amdgcn_update_dpp(0, __builtin_bit_cast(int, x), CTRL, 0xF, 0xF, true));
}
__device__ __forceinline__ float wsum(float v) {
  v += dppmov<0xB1>(v);
  v += dppmov<0x4E>(v);
  v += dppmov<0x141>(v);
  v += dppmov<0x140>(v);
  v += __builtin_bit_cast(float, __builtin_amdgcn_ds_swizzle(__builtin_bit_cast(int, v), 0x401F));
  float a = __builtin_bit_cast(float, __builtin_amdgcn_readlane(__builtin_bit_cast(int, v), 0));
  float b = __builtin_bit_cast(float, __builtin_amdgcn_readlane(__builtin_bit_cast(int, v), 32));
  return a + b;
}

// ---------------- async global->LDS staging with both-sides XOR swizzle ----------------
__device__ __forceinline__ void stage_rows(char* lds, const char* g, size_t gstride,
                                           int nIss, int wid, int nw, int lane) {
  for (int is = wid; is < nIss; is += nw) {
    const int row = (is << 3) + (lane >> 3);
    const int s = lane & 7;
    const char* gp = g + (size_t)row * gstride + (((s ^ (row & 7))) << 4);
    __builtin_amdgcn_global_load_lds((const __attribute__((address_space(1))) void*)gp,
                                     (__attribute__((address_space(3))) void*)(lds + ((size_t)is << 10)),
                                     16, 0, 0);
  }
}
__device__ __forceinline__ bf16x8 frag_ld(const char* lds, int row, int kslot) {
  return *(const bf16x8*)(lds + row * 128 + ((kslot ^ (row & 7)) << 4));
}

// ---------------- embed + pad mask (float addend: 0 or -5e8) ----------------
__global__ void embed_k(const int* __restrict__ x, const float* __restrict__ etab,
                        const float* __restrict__ ptab, const float* __restrict__ cls,
                        float* __restrict__ h, float* __restrict__ padf) {
  const int tok = blockIdx.x;
  const int b = tok >> 9, t = tok & 511;
  const int lane = threadIdx.x;
  float4 o0, o1;
  int isPad = 0;
  if (t == 0) {
    o0 = ((const float4*)cls)[lane];
    o1 = ((const float4*)cls)[64 + lane];
  } else {
    const int id = x[b * TT + (t - 1)];
    isPad = (id == 0);
    const float m = isPad ? 0.0f : 1.0f;
    const float4* e  = (const float4*)(etab + (size_t)id * DD);
    const float4* pp = (const float4*)(ptab + (size_t)(t - 1) * DD);
    float4 e0 = e[lane], e1 = e[64 + lane];
    float4 p0 = pp[lane], p1 = pp[64 + lane];
    o0.x = e0.x * m + p0.x; o0.y = e0.y * m + p0.y;
    o0.z = e0.z * m + p0.z; o0.w = e0.w * m + p0.w;
    o1.x = e1.x * m + p1.x; o1.y = e1.y * m + p1.y;
    o1.z = e1.z * m + p1.z; o1.w = e1.w * m + p1.w;
  }
  float4* hp = (float4*)(h + (size_t)tok * DD);
  hp[lane] = o0; hp[64 + lane] = o1;
  if (lane == 0) padf[tok] = isPad ? -5.0e8f : 0.0f;
}

// ---------------- weight transpose + bf16 convert ----------------
__global__ __launch_bounds__(256) void wprep(const float* __restrict__ Wq, const float* __restrict__ Wk,
                                             const float* __restrict__ Wv, const float* __restrict__ Wo,
                                             const float* __restrict__ f1w, const float* __restrict__ f2w,
                                             unsigned short* __restrict__ qkvT, unsigned short* __restrict__ woT,
                                             unsigned short* __restrict__ f1T, unsigned short* __restrict__ f2T) {
  const int z = blockIdx.z;
  const float* src; unsigned short* dst; int K, N;
  if (z < 12) { int l = z / 3, w = z % 3;
    src = (w == 0 ? Wq : w == 1 ? Wk : Wv) + (size_t)l * 512 * 512; K = 512; N = 512;
    dst = qkvT + (size_t)l * 1536 * 512 + (size_t)w * 512 * 512;
  } else if (z < 16) { int l = z - 12; src = Wo + (size_t)l * 512 * 512; K = 512; N = 512;
    dst = woT + (size_t)l * 512 * 512;
  } else if (z < 20) { int l = z - 16; src = f1w + (size_t)l * 512 * 256; K = 512; N = 256;
    dst = f1T + (size_t)l * 256 * 512;
  } else { int l = z - 20; src = f2w + (size_t)l * 256 * 512; K = 256; N = 512;
    dst = f2T + (size_t)l * 512 * 256;
  }
  const int n0 = blockIdx.x * 32, k0 = blockIdx.y * 32;
  if (n0 >= N || k0 >= K) return;
  __shared__ float tbuf[32][33];
  const int tx = threadIdx.x & 31, ty = threadIdx.x >> 5;
#pragma unroll
  for (int i = 0; i < 32; i += 8)
    tbuf[ty + i][tx] = src[(size_t)(k0 + ty + i) * N + n0 + tx];
  __syncthreads();
#pragma unroll
  for (int i = 0; i < 32; i += 8)
    dst[(size_t)(n0 + ty + i) * K + k0 + tx] = f2b(tbuf[tx][ty + i]);
}

// ---------------- layernorm: f32 out + bf16 out ----------------
__global__ __launch_bounds__(256) void ln_rows(const float* __restrict__ in,
                                               float* __restrict__ outf,
                                               unsigned short* __restrict__ outb,
                                               const float* __restrict__ g,
                                               const float* __restrict__ b) {
  const int wave = threadIdx.x >> 6, lane = threadIdx.x & 63;
  const int row = blockIdx.x * 4 + wave;
  const float* p = in + (size_t)row * DD;
  float4 a = ((const float4*)p)[lane];
  float4 c = ((const float4*)p)[64 + lane];
  float v[8] = {a.x, a.y, a.z, a.w, c.x, c.y, c.z, c.w};
  float s = 0.f;
#pragma unroll
  for (int i = 0; i < 8; ++i) s += v[i];
  const float m = wsum(s) * (1.0f / 512.0f);
  float sq = 0.f;
#pragma unroll
  for (int i = 0; i < 8; ++i) { float d = v[i] - m; sq = fmaf(d, d, sq); }
  const float rs = rsqrtf(wsum(sq) * (1.0f / 512.0f) + 1e-5f);
  float4 g0 = ((const float4*)g)[lane], g1 = ((const float4*)g)[64 + lane];
  float4 b0 = ((const float4*)b)[lane], b1 = ((const float4*)b)[64 + lane];
  float r[8];
  r[0] = (v[0] - m) * rs * g0.x + b0.x; r[1] = (v[1] - m) * rs * g0.y + b0.y;
  r[2] = (v[2] - m) * rs * g0.z + b0.z; r[3] = (v[3] - m) * rs * g0.w + b0.w;
  r[4] = (v[4] - m) * rs * g1.x + b1.x; r[5] = (v[5] - m) * rs * g1.y + b1.y;
  r[6] = (v[6] - m) * rs * g1.z + b1.z; r[7] = (v[7] - m) * rs * g1.w + b1.w;
  float4* op = (float4*)(outf + (size_t)row * DD);
  op[lane] = make_float4(r[0], r[1], r[2], r[3]);
  op[64 + lane] = make_float4(r[4], r[5], r[6], r[7]);
  ushort4 q0, q1;
  q0.x = f2b(r[0]); q0.y = f2b(r[1]); q0.z = f2b(r[2]); q0.w = f2b(r[3]);
  q1.x = f2b(r[4]); q1.y = f2b(r[5]); q1.z = f2b(r[6]); q1.w = f2b(r[7]);
  ushort4* ob = (ushort4*)(outb + (size_t)row * DD);
  ob[lane] = q0; ob[64 + lane] = q1;
}

// h = LN1(t + xin)*g1 + b1 + h ; then xinb = bf16(LN2(h)*g2 + b2)
__global__ __launch_bounds__(256) void resid_ln2(const float* __restrict__ t,
                                                 const float* __restrict__ xin,
                                                 float* __restrict__ h,
                                                 const float* __restrict__ g1,
                                                 const float* __restrict__ b1,
                                                 const float* __restrict__ g2,
                                                 const float* __restrict__ b2,
                                                 unsigned short* __restrict__ xinb) {
  const int wave = threadIdx.x >> 6, lane = threadIdx.x & 63;
  const int row = blockIdx.x * 4 + wave;
  const float* tp = t + (size_t)row * DD;
  const float* xp = xin + (size_t)row * DD;
  float4 t0 = ((const float4*)tp)[lane], t1 = ((const float4*)tp)[64 + lane];
  float4 x0 = ((const float4*)xp)[lane], x1 = ((const float4*)xp)[64 + lane];
  float v[8] = {t0.x + x0.x, t0.y + x0.y, t0.z + x0.z, t0.w + x0.w,
                t1.x + x1.x, t1.y + x1.y, t1.z + x1.z, t1.w + x1.w};
  float s = 0.f;
#pragma unroll
  for (int i = 0; i < 8; ++i) s += v[i];
  const float m = wsum(s) * (1.0f / 512.0f);
  float sq = 0.f;
#pragma unroll
  for (int i = 0; i < 8; ++i) { float d = v[i] - m; sq = fmaf(d, d, sq); }
  const float rs = rsqrtf(wsum(sq) * (1.0f / 512.0f) + 1e-5f);
  float4 g0 = ((const float4*)g1)[lane], g1v = ((const float4*)g1)[64 + lane];
  float4 c0 = ((const float4*)b1)[lane], c1 = ((const float4*)b1)[64 + lane];
  float4* hp = (float4*)(h + (size_t)row * DD);
  float4 h0 = hp[lane], h1 = hp[64 + lane];
  float a[8];
  a[0] = h0.x + (v[0] - m) * rs * g0.x + c0.x;  a[1] = h0.y + (v[1] - m) * rs * g0.y + c0.y;
  a[2] = h0.z + (v[2] - m) * rs * g0.z + c0.z;  a[3] = h0.w + (v[3] - m) * rs * g0.w + c0.w;
  a[4] = h1.x + (v[4] - m) * rs * g1v.x + c1.x; a[5] = h1.y + (v[5] - m) * rs * g1v.y + c1.y;
  a[6] = h1.z + (v[6] - m) * rs * g1v.z + c1.z; a[7] = h1.w + (v[7] - m) * rs * g1v.w + c1.w;
  hp[lane] = make_float4(a[0], a[1], a[2], a[3]);
  hp[64 + lane] = make_float4(a[4], a[5], a[6], a[7]);
  // second LN
  float s2 = 0.f;
#pragma unroll
  for (int i = 0; i < 8; ++i) s2 += a[i];
  const float m2 = wsum(s2) * (1.0f / 512.0f);
  float sq2 = 0.f;
#pragma unroll
  for (int i = 0; i < 8; ++i) { float d = a[i] - m2; sq2 = fmaf(d, d, sq2); }
  const float rs2 = rsqrtf(wsum(sq2) * (1.0f / 512.0f) + 1e-5f);
  float4 G0 = ((const float4*)g2)[lane], G1 = ((const float4*)g2)[64 + lane];
  float4 B0 = ((const float4*)b2)[lane], B1 = ((const float4*)b2)[64 + lane];
  ushort4 q0, q1;
  q0.x = f2b((a[0] - m2) * rs2 * G0.x + B0.x); q0.y = f2b((a[1] - m2) * rs2 * G0.y + B0.y);
  q0.z = f2b((a[2] - m2) * rs2 * G0.z + B0.z); q0.w = f2b((a[3] - m2) * rs2 * G0.w + B0.w);
  q1.x = f2b((a[4] - m2) * rs2 * G1.x + B1.x); q1.y = f2b((a[5] - m2) * rs2 * G1.y + B1.y);
  q1.z = f2b((a[6] - m2) * rs2 * G1.z + B1.z); q1.w = f2b((a[7] - m2) * rs2 * G1.w + B1.w);
  ushort4* ob = (ushort4*)(xinb + (size_t)row * DD);
  ob[lane] = q0; ob[64 + lane] = q1;
}

// ---------------- generic bf16 MFMA GEMM: C = A[M,K] @ Bt[N,K]^T ----------------
template<int BM, int BN, int WM, int WN, int EPI>
__global__ __launch_bounds__(256) void mgemm(const unsigned short* __restrict__ A,
                                             const unsigned short* __restrict__ Bt,
                                             void* __restrict__ C0, void* __restrict__ C1,
                                             void* __restrict__ C2,
                                             const float* __restrict__ bias,
                                             int M, int N, int K) {
  constexpr int NW = (BM / WM) * (BN / WN);
  constexpr int FM = WM / 16, FN = WN / 16;
  __shared__ char smem[(BM + BN) * 128];
  char* sA = smem; char* sB = smem + BM * 128;
  const int tid = threadIdx.x, lane = tid & 63, wid = tid >> 6;
  const int row0 = blockIdx.y * BM, col0 = blockIdx.x * BN;
  const int wrow = (wid / (BN / WN)) * WM, wcol = (wid % (BN / WN)) * WN;
  f32x4 acc[FM][FN] = {};
  const char* Ag = (const char*)(A + (size_t)row0 * K);
  const char* Bg = (const char*)(Bt + (size_t)col0 * K);
  for (int k0 = 0; k0 < K; k0 += 64) {
    __syncthreads();
    stage_rows(sA, Ag + (size_t)k0 * 2, (size_t)K * 2, BM / 8, wid, NW, lane);
    stage_rows(sB, Bg + (size_t)k0 * 2, (size_t)K * 2, BN / 8, wid, NW, lane);
    __syncthreads();
#pragma unroll
    for (int kk = 0; kk < 2; ++kk) {
      bf16x8 af[FM], bfr[FN];
#pragma unroll
      for (int mi = 0; mi < FM; ++mi)
        af[mi] = frag_ld(sA, wrow + mi * 16 + (lane & 15), kk * 4 + (lane >> 4));
#pragma unroll
      for (int ni = 0; ni < FN; ++ni)
        bfr[ni] = frag_ld(sB, wcol + ni * 16 + (lane & 15), kk * 4 + (lane >> 4));
#pragma unroll
      for (int mi = 0; mi < FM; ++mi)
#pragma unroll
        for (int ni = 0; ni < FN; ++ni)
          acc[mi][ni] = __builtin_amdgcn_mfma_f32_16x16x32_bf16(af[mi], bfr[ni], acc[mi][ni], 0, 0, 0);
    }
  }
#pragma unroll
  for (int mi = 0; mi < FM; ++mi)
#pragma unroll
    for (int ni = 0; ni < FN; ++ni) {
      const int colb = col0 + wcol + ni * 16;
      const int col = colb + (lane & 15);
      const int rowb = row0 + wrow + mi * 16 + (lane >> 4) * 4;
      if (EPI == 1 && (colb >> 9) == 2) {      // V segment -> vt[bh][d][t]
        const int cc = col - 1024, hh = cc >> 6, d = cc & 63, b = rowb >> 9, t = rowb & 511;
        ushort4 pk;
        pk.x = f2b(acc[mi][ni][0]); pk.y = f2b(acc[mi][ni][1]);
        pk.z = f2b(acc[mi][ni][2]); pk.w = f2b(acc[mi][ni][3]);
        *(ushort4*)((unsigned short*)C2 + (((size_t)(b * 8 + hh) * 64 + d) << 9) + t) = pk;
      } else {
#pragma unroll
        for (int r = 0; r < 4; ++r) {
          const int row = rowb + r;
          const float v = acc[mi][ni][r];
          if (EPI == 0) {
            ((float*)C0)[(size_t)row * N + col] = v;
          } else if (EPI == 1) {
            if (colb < 512) ((unsigned short*)C0)[(size_t)row * 512 + col] = f2b(v);
            else            ((unsigned short*)C1)[(size_t)row * 512 + (col - 512)] = f2b(v);
          } else if (EPI == 2) {
            ((unsigned short*)C0)[(size_t)row * N + col] = f2b(gelu_f(v + bias[col]));
          } else {
            ((float*)C0)[(size_t)row * N + col] += v + bias[col];
          }
        }
      }
    }
}

// ---------------- fused attention: S=QK^T -> entmax15 -> P@V, one wave = 16 q-rows ----
// grid (TC/64, B*H); block 256 = 4 waves. No __syncthreads; wave-private LDS chunk.
__global__ __launch_bounds__(256, 2) void attn_fused(const unsigned short* __restrict__ q,
                                                     const unsigned short* __restrict__ k,
                                                     const unsigned short* __restrict__ vt,
                                                     const float* __restrict__ padf,
                                                     unsigned short* __restrict__ attnout) {
  __shared__ char sP[4][2048];
  const int bh = blockIdx.y, b = bh >> 3, hh = bh & 7;
  const int wid = threadIdx.x >> 6, lane = threadIdx.x & 63;
  const int q0 = blockIdx.x * 64 + wid * 16;
  const int col16 = lane & 15, g4 = lane >> 4;
  const unsigned short* qb = q + ((size_t)(b * TC + q0)) * DD + hh * HD;
  const unsigned short* kb = k + ((size_t)(b * TC)) * DD + hh * HD;
  const unsigned short* vb = vt + ((size_t)bh * 64) * 512;

  // ---- S = Q K^T : 64 MFMA, operands direct from global (L2-hot) ----
  f32x4 acc[32] = {};
  const unsigned short* qrow = qb + (size_t)col16 * DD + g4 * 8;
  bf16x8 aq0 = *(const bf16x8*)(qrow);
  bf16x8 aq1 = *(const bf16x8*)(qrow + 32);
#pragma unroll 8
  for (int ni = 0; ni < 32; ++ni) {
    const unsigned short* krow = kb + (size_t)(16 * ni + col16) * DD + g4 * 8;
    bf16x8 b0 = *(const bf16x8*)(krow);
    bf16x8 b1 = *(const bf16x8*)(krow + 32);
    acc[ni] = __builtin_amdgcn_mfma_f32_16x16x32_bf16(aq0, b0, acc[ni], 0, 0, 0);
    acc[ni] = __builtin_amdgcn_mfma_f32_16x16x32_bf16(aq1, b1, acc[ni], 0, 0, 0);
  }

  // ---- scale (/8 /2), key-pad mask, row max ----
  const int btc = b * TC;
  float mx[4] = {-3.4e38f, -3.4e38f, -3.4e38f, -3.4e38f};
#pragma unroll
  for (int ni = 0; ni < 32; ++ni) {
    const float ma = padf[btc + 16 * ni + col16];
#pragma unroll
    for (int r = 0; r < 4; ++r) {
      acc[ni][r] = fmaf(acc[ni][r], 0.0625f, ma);
      mx[r] = fmaxf(mx[r], acc[ni][r]);
    }
  }
#pragma unroll
  for (int r = 0; r < 4; ++r) {
#pragma unroll
    for (int m = 1; m <= 8; m <<= 1) mx[r] = fmaxf(mx[r], __shfl_xor(mx[r], m, 64));
  }
#pragma unroll
  for (int ni = 0; ni < 32; ++ni)
#pragma unroll
    for (int r = 0; r < 4; ++r) acc[ni][r] -= mx[r];

  // ---- Newton on f(tau)=sum relu(v-tau)^2 = 1 (convex, monotone from below) ----
  float tau[4] = {-1.f, -1.f, -1.f, -1.f};
#pragma unroll
  for (int it = 0; it < 8; ++it) {
    float s1[4] = {0, 0, 0, 0}, s2[4] = {0, 0, 0, 0};
#pragma unroll
    for (int ni = 0; ni < 32; ++ni)
#pragma unroll
      for (int r = 0; r < 4; ++r) {
        const float d = fmaxf(acc[ni][r] - tau[r], 0.f);
        s1[r] += d; s2[r] = fmaf(d, d, s2[r]);
      }
#pragma unroll
    for (int r = 0; r < 4; ++r) {
#pragma unroll
      for (int m = 1; m <= 8; m <<= 1) {
        s1[r] += __shfl_xor(s1[r], m, 64);
        s2[r] += __shfl_xor(s2[r], m, 64);
      }
      tau[r] += (s2[r] - 1.0f) / (2.0f * fmaxf(s1[r], 1e-20f));
    }
  }
  // ---- closed-form tau* over support {v > tau}, then p = relu(v-tau*)^2, renorm ----
  {
    float c1[4] = {0, 0, 0, 0}, s1[4] = {0, 0, 0, 0}, s2[4] = {0, 0, 0, 0};
#pragma unroll
    for (int ni = 0; ni < 32; ++ni)
#pragma unroll
      for (int r = 0; r < 4; ++r) {
        const float vv = acc[ni][r];
        const float msk = (vv > tau[r]) ? 1.0f : 0.0f;
        c1[r] += msk; s1[r] += msk * vv; s2[r] = fmaf(msk * vv, vv, s2[r]);
      }
#pragma unroll
    for (int r = 0; r < 4; ++r) {
#pragma unroll
      for (int m = 1; m <= 8; m <<= 1) {
        c1[r] += __shfl_xor(c1[r], m, 64);
        s1[r] += __shfl_xor(s1[r], m, 64);
        s2[r] += __shfl_xor(s2[r], m, 64);
      }
      const float disc = fmaxf(s1[r] * s1[r] - c1[r] * s2[r] + c1[r], 0.f);
      tau[r] = (s1[r] - sqrtf(disc)) / c1[r];
    }
  }
  float inv[4];
  {
    float ss[4] = {0, 0, 0, 0};
#pragma unroll
    for (int ni = 0; ni < 32; ++ni)
#pragma unroll
      for (int r = 0; r < 4; ++r) {
        const float d = fmaxf(acc[ni][r] - tau[r], 0.f);
        acc[ni][r] = d * d;
        ss[r] = fmaf(d, d, ss[r]);
      }
#pragma unroll
    for (int r = 0; r < 4; ++r) {
#pragma unroll
      for (int m = 1; m <= 8; m <<= 1) ss[r] += __shfl_xor(ss[r], m, 64);
      inv[r] = 1.0f / ss[r];
    }
  }

  // ---- P@V: per 64-key chunk, write P (bf16, swizzled) to wave-private LDS, MFMA ----
  char* myP = sP[wid];
  f32x4 acc2[4] = {};
#pragma unroll
  for (int c = 0; c < 8; ++c) {
#pragma unroll
    for (int nj = 0; nj < 4; ++nj) {
      const int ni = 4 * c + nj;
#pragma unroll
      for (int r = 0; r < 4; ++r) {
        const int lq = g4 * 4 + r;
        const int ck = nj * 16 + col16;
        *(unsigned short*)(myP + lq * 128 + ((((ck >> 3) ^ (lq & 7))) << 4) + ((ck & 7) << 1)) =
            f2b(acc[ni][r] * inv[r]);
      }
    }
#pragma unroll
    for (int kk = 0; kk < 2; ++kk) {
      const bf16x8 pa = frag_ld(myP, col16, kk * 4 + g4);
#pragma unroll
      for (int n2 = 0; n2 < 4; ++n2) {
        const unsigned short* vrow = vb + (size_t)(16 * n2 + col16) * 512 + c * 64 + kk * 32 + g4 * 8;
        acc2[n2] = __builtin_amdgcn_mfma_f32_16x16x32_bf16(pa, *(const bf16x8*)vrow, acc2[n2], 0, 0, 0);
      }
    }
  }
#pragma unroll
  for (int n2 = 0; n2 < 4; ++n2)
#pragma unroll
    for (int r = 0; r < 4; ++r)
      attnout[((size_t)(b * TC + q0 + g4 * 4 + r)) * DD + hh * HD + 16 * n2 + col16] = f2b(acc2[n2][r]);
}

// ---------------- head ----------------
__global__ void head_k(const float* __restrict__ h, const float* __restrict__ w1,
                       const float* __restrict__ b1, const float* __restrict__ w2,
                       const float* __restrict__ b2, float* __restrict__ out) {
  __shared__ float z[BB][HEADH];
  const int tid = threadIdx.x;
  const int b = tid >> 5, j = tid & 31;
  const float* hr = h + (size_t)(b * TC) * DD;
  float s = 0.f;
  for (int kk = 0; kk < DD; ++kk) s = fmaf(hr[kk], w1[kk * HEADH + j], s);
  z[b][j] = fmaxf(s + b1[j], 0.f);
  __syncthreads();
  if (tid < BB) {
    float acc = b2[0];
#pragma unroll
    for (int q2 = 0; q2 < HEADH; ++q2) acc = fmaf(z[tid][q2], w2[q2], acc);
    out[tid] = acc;
  }
}

// ---------------- workspace layout ----------------
// h 8M | xin 8M | t 8M | xinb 4M | q 4M | k 4M | vt 4M | at 4M | mid 2M |
// qkvT 6M | woT 2M | f1T 1M | f2T 1M | padf 16K   => 56 MiB + 16 KiB
#define WS_NEED 58736640ull
static __device__ __align__(256) unsigned char g_fallback_ws[WS_NEED];

extern "C" void kernel_launch(void* const* d_in, const int* in_sizes, int n_in,
                              void* d_out, int out_size, void* d_ws, size_t ws_size,
                              hipStream_t stream) {
  const int*   x     = (const int*)d_in[0];
  const float* etab  = (const float*)d_in[1];
  const float* ptab  = (const float*)d_in[2];
  const float* cls   = (const float*)d_in[3];
  const float* Wq    = (const float*)d_in[4];
  const float* Wk    = (const float*)d_in[5];
  const float* Wv    = (const float*)d_in[6];
  const float* Wo    = (const float*)d_in[7];
  const float* an_g  = (const float*)d_in[8];
  const float* an_b  = (const float*)d_in[9];
  const float* ln1_g = (const float*)d_in[10];
  const float* ln1_b = (const float*)d_in[11];
  const float* ln2_g = (const float*)d_in[12];
  const float* ln2_b = (const float*)d_in[13];
  const float* f1_w  = (const float*)d_in[14];
  const float* f1_b  = (const float*)d_in[15];
  const float* f2_w  = (const float*)d_in[16];
  const float* f2_b  = (const float*)d_in[17];
  const float* h1_w  = (const float*)d_in[18];
  const float* h1_b  = (const float*)d_in[19];
  const float* h2_w  = (const float*)d_in[20];
  const float* h2_b  = (const float*)d_in[21];
  float* out = (float*)d_out;

  void* wsbase = d_ws;
  if (ws_size < WS_NEED) hipGetSymbolAddress(&wsbase, HIP_SYMBOL(g_fallback_ws));
  char* base = (char*)wsbase;
  const size_t MB = 1048576;
  float* h_    = (float*)(base);
  float* xin_  = (float*)(base + 8 * MB);
  float* t_    = (float*)(base + 16 * MB);
  unsigned short* xinb_ = (unsigned short*)(base + 24 * MB);
  unsigned short* q_    = (unsigned short*)(base + 28 * MB);
  unsigned short* k_    = (unsigned short*)(base + 32 * MB);
  unsigned short* vt_   = (unsigned short*)(base + 36 * MB);
  unsigned short* at_   = (unsigned short*)(base + 40 * MB);
  unsigned short* mid_  = (unsigned short*)(base + 44 * MB);
  unsigned short* qkvT_ = (unsigned short*)(base + 46 * MB);
  unsigned short* woT_  = (unsigned short*)(base + 52 * MB);
  unsigned short* f1T_  = (unsigned short*)(base + 54 * MB);
  unsigned short* f2T_  = (unsigned short*)(base + 55 * MB);
  float* padf_ = (float*)(base + 56 * MB);

  wprep<<<dim3(16, 16, 24), 256, 0, stream>>>(Wq, Wk, Wv, Wo, f1_w, f2_w, qkvT_, woT_, f1T_, f2T_);
  embed_k<<<NTOK, 64, 0, stream>>>(x, etab, ptab, cls, h_, padf_);

  for (int l = 0; l < LL; ++l) {
    ln_rows<<<NTOK / 4, 256, 0, stream>>>(h_, xin_, xinb_, ln1_g + l * DD, ln1_b + l * DD);
    mgemm<128, 128, 64, 64, 1><<<dim3(12, 32), 256, 0, stream>>>(
        xinb_, qkvT_ + (size_t)l * 1536 * 512, q_, k_, vt_, nullptr, NTOK, 1536, 512);
    attn_fused<<<dim3(TC / 64, BB * HH), 256, 0, stream>>>(q_, k_, vt_, padf_, at_);
    mgemm<128, 128, 64, 64, 0><<<dim3(4, 32), 256, 0, stream>>>(
        at_, woT_ + (size_t)l * 512 * 512, t_, nullptr, nullptr, nullptr, NTOK, 512, 512);
    resid_ln2<<<NTOK / 4, 256, 0, stream>>>(t_, xin_, h_, an_g + l * DD, an_b + l * DD,
                                            ln2_g + l * DD, ln2_b + l * DD, xinb_);
    mgemm<64, 64, 32, 32, 2><<<dim3(4, 64), 256, 0, stream>>>(
        xinb_, f1T_ + (size_t)l * 256 * 512, mid_, nullptr, nullptr, f1_b + l * FF, NTOK, 256, 512);
    mgemm<64, 128, 32, 64, 3><<<dim3(4, 64), 256, 0, stream>>>(
        mid_, f2T_ + (size_t)l * 512 * 256, h_, nullptr, nullptr, f2_b + l * DD, NTOK, 512, 256);
  }

  head_k<<<1, 256, 0, stream>>>(h_, h1_w, h1_b, h2_w, h2_b, out);
}

// Round 7
// 606.991 us; speedup vs baseline: 1.5808x; 1.5808x over previous
//
#include <hip/hip_runtime.h>
#include <hip/hip_bf16.h>
#include <math.h>

// ---------------- model dims ----------------
#define BB    8
#define TT    511
#define TC    512
#define DD    512
#define HH    8
#define HD    64
#define LL    4
#define FF    256
#define HEADH 32
#define NTOK  (BB*TC)      // 4096

typedef __bf16 bf16x8 __attribute__((ext_vector_type(8)));
typedef float  f32x4  __attribute__((ext_vector_type(4)));

__device__ __forceinline__ unsigned short f2b(float v) {
  __bf16 t = (__bf16)v;
  return __builtin_bit_cast(unsigned short, t);
}
__device__ __forceinline__ float gelu_f(float x) {
  return 0.5f * x * (1.0f + erff(x * 0.7071067811865476f));
}

// ---------------- fast wave reduce (64-lane): DPP + ds_swizzle + readlane ----------------
template<int CTRL>
__device__ __forceinline__ float dppmov(float x) {
  return __builtin_bit_cast(float,
      __builtin_amdgcn_update_dpp(0, __builtin_bit_cast(int, x), CTRL, 0xF, 0xF, true));
}
__device__ __forceinline__ float wsum(float v) {
  v += dppmov<0xB1>(v);
  v += dppmov<0x4E>(v);
  v += dppmov<0x141>(v);
  v += dppmov<0x140>(v);
  v += __builtin_bit_cast(float, __builtin_amdgcn_ds_swizzle(__builtin_bit_cast(int, v), 0x401F));
  float a = __builtin_bit_cast(float, __builtin_amdgcn_readlane(__builtin_bit_cast(int, v), 0));
  float b = __builtin_bit_cast(float, __builtin_amdgcn_readlane(__builtin_bit_cast(int, v), 32));
  return a + b;
}

// ---------------- async global->LDS staging with both-sides XOR swizzle ----------------
__device__ __forceinline__ void stage_rows(char* lds, const char* g, size_t gstride,
                                           int nIss, int wid, int nw, int lane) {
  for (int is = wid; is < nIss; is += nw) {
    const int row = (is << 3) + (lane >> 3);
    const int s = lane & 7;
    const char* gp = g + (size_t)row * gstride + (((s ^ (row & 7))) << 4);
    __builtin_amdgcn_global_load_lds((const __attribute__((address_space(1))) void*)gp,
                                     (__attribute__((address_space(3))) void*)(lds + ((size_t)is << 10)),
                                     16, 0, 0);
  }
}
__device__ __forceinline__ bf16x8 frag_ld(const char* lds, int row, int kslot) {
  return *(const bf16x8*)(lds + row * 128 + ((kslot ^ (row & 7)) << 4));
}

// ---------------- embed + pad mask (float addend: 0 or -5e8) ----------------
__global__ void embed_k(const int* __restrict__ x, const float* __restrict__ etab,
                        const float* __restrict__ ptab, const float* __restrict__ cls,
                        float* __restrict__ h, float* __restrict__ padf) {
  const int tok = blockIdx.x;
  const int b = tok >> 9, t = tok & 511;
  const int lane = threadIdx.x;
  float4 o0, o1;
  int isPad = 0;
  if (t == 0) {
    o0 = ((const float4*)cls)[lane];
    o1 = ((const float4*)cls)[64 + lane];
  } else {
    const int id = x[b * TT + (t - 1)];
    isPad = (id == 0);
    const float m = isPad ? 0.0f : 1.0f;
    const float4* e  = (const float4*)(etab + (size_t)id * DD);
    const float4* pp = (const float4*)(ptab + (size_t)(t - 1) * DD);
    float4 e0 = e[lane], e1 = e[64 + lane];
    float4 p0 = pp[lane], p1 = pp[64 + lane];
    o0.x = e0.x * m + p0.x; o0.y = e0.y * m + p0.y;
    o0.z = e0.z * m + p0.z; o0.w = e0.w * m + p0.w;
    o1.x = e1.x * m + p1.x; o1.y = e1.y * m + p1.y;
    o1.z = e1.z * m + p1.z; o1.w = e1.w * m + p1.w;
  }
  float4* hp = (float4*)(h + (size_t)tok * DD);
  hp[lane] = o0; hp[64 + lane] = o1;
  if (lane == 0) padf[tok] = isPad ? -5.0e8f : 0.0f;
}

// ---------------- weight transpose + bf16 convert ----------------
__global__ __launch_bounds__(256) void wprep(const float* __restrict__ Wq, const float* __restrict__ Wk,
                                             const float* __restrict__ Wv, const float* __restrict__ Wo,
                                             const float* __restrict__ f1w, const float* __restrict__ f2w,
                                             unsigned short* __restrict__ qkvT, unsigned short* __restrict__ woT,
                                             unsigned short* __restrict__ f1T, unsigned short* __restrict__ f2T) {
  const int z = blockIdx.z;
  const float* src; unsigned short* dst; int K, N;
  if (z < 12) { int l = z / 3, w = z % 3;
    src = (w == 0 ? Wq : w == 1 ? Wk : Wv) + (size_t)l * 512 * 512; K = 512; N = 512;
    dst = qkvT + (size_t)l * 1536 * 512 + (size_t)w * 512 * 512;
  } else if (z < 16) { int l = z - 12; src = Wo + (size_t)l * 512 * 512; K = 512; N = 512;
    dst = woT + (size_t)l * 512 * 512;
  } else if (z < 20) { int l = z - 16; src = f1w + (size_t)l * 512 * 256; K = 512; N = 256;
    dst = f1T + (size_t)l * 256 * 512;
  } else { int l = z - 20; src = f2w + (size_t)l * 256 * 512; K = 256; N = 512;
    dst = f2T + (size_t)l * 512 * 256;
  }
  const int n0 = blockIdx.x * 32, k0 = blockIdx.y * 32;
  if (n0 >= N || k0 >= K) return;
  __shared__ float tbuf[32][33];
  const int tx = threadIdx.x & 31, ty = threadIdx.x >> 5;
#pragma unroll
  for (int i = 0; i < 32; i += 8)
    tbuf[ty + i][tx] = src[(size_t)(k0 + ty + i) * N + n0 + tx];
  __syncthreads();
#pragma unroll
  for (int i = 0; i < 32; i += 8)
    dst[(size_t)(n0 + ty + i) * K + k0 + tx] = f2b(tbuf[tx][ty + i]);
}

// ---------------- layernorm: f32 out + bf16 out ----------------
__global__ __launch_bounds__(256) void ln_rows(const float* __restrict__ in,
                                               float* __restrict__ outf,
                                               unsigned short* __restrict__ outb,
                                               const float* __restrict__ g,
                                               const float* __restrict__ b) {
  const int wave = threadIdx.x >> 6, lane = threadIdx.x & 63;
  const int row = blockIdx.x * 4 + wave;
  const float* p = in + (size_t)row * DD;
  float4 a = ((const float4*)p)[lane];
  float4 c = ((const float4*)p)[64 + lane];
  float v[8] = {a.x, a.y, a.z, a.w, c.x, c.y, c.z, c.w};
  float s = 0.f;
#pragma unroll
  for (int i = 0; i < 8; ++i) s += v[i];
  const float m = wsum(s) * (1.0f / 512.0f);
  float sq = 0.f;
#pragma unroll
  for (int i = 0; i < 8; ++i) { float d = v[i] - m; sq = fmaf(d, d, sq); }
  const float rs = rsqrtf(wsum(sq) * (1.0f / 512.0f) + 1e-5f);
  float4 g0 = ((const float4*)g)[lane], g1 = ((const float4*)g)[64 + lane];
  float4 b0 = ((const float4*)b)[lane], b1 = ((const float4*)b)[64 + lane];
  float r[8];
  r[0] = (v[0] - m) * rs * g0.x + b0.x; r[1] = (v[1] - m) * rs * g0.y + b0.y;
  r[2] = (v[2] - m) * rs * g0.z + b0.z; r[3] = (v[3] - m) * rs * g0.w + b0.w;
  r[4] = (v[4] - m) * rs * g1.x + b1.x; r[5] = (v[5] - m) * rs * g1.y + b1.y;
  r[6] = (v[6] - m) * rs * g1.z + b1.z; r[7] = (v[7] - m) * rs * g1.w + b1.w;
  float4* op = (float4*)(outf + (size_t)row * DD);
  op[lane] = make_float4(r[0], r[1], r[2], r[3]);
  op[64 + lane] = make_float4(r[4], r[5], r[6], r[7]);
  ushort4 q0, q1;
  q0.x = f2b(r[0]); q0.y = f2b(r[1]); q0.z = f2b(r[2]); q0.w = f2b(r[3]);
  q1.x = f2b(r[4]); q1.y = f2b(r[5]); q1.z = f2b(r[6]); q1.w = f2b(r[7]);
  ushort4* ob = (ushort4*)(outb + (size_t)row * DD);
  ob[lane] = q0; ob[64 + lane] = q1;
}

// h = LN1(t + xin)*g1 + b1 + h ; then xinb = bf16(LN2(h)*g2 + b2)
__global__ __launch_bounds__(256) void resid_ln2(const float* __restrict__ t,
                                                 const float* __restrict__ xin,
                                                 float* __restrict__ h,
                                                 const float* __restrict__ g1,
                                                 const float* __restrict__ b1,
                                                 const float* __restrict__ g2,
                                                 const float* __restrict__ b2,
                                                 unsigned short* __restrict__ xinb) {
  const int wave = threadIdx.x >> 6, lane = threadIdx.x & 63;
  const int row = blockIdx.x * 4 + wave;
  const float* tp = t + (size_t)row * DD;
  const float* xp = xin + (size_t)row * DD;
  float4 t0 = ((const float4*)tp)[lane], t1 = ((const float4*)tp)[64 + lane];
  float4 x0 = ((const float4*)xp)[lane], x1 = ((const float4*)xp)[64 + lane];
  float v[8] = {t0.x + x0.x, t0.y + x0.y, t0.z + x0.z, t0.w + x0.w,
                t1.x + x1.x, t1.y + x1.y, t1.z + x1.z, t1.w + x1.w};
  float s = 0.f;
#pragma unroll
  for (int i = 0; i < 8; ++i) s += v[i];
  const float m = wsum(s) * (1.0f / 512.0f);
  float sq = 0.f;
#pragma unroll
  for (int i = 0; i < 8; ++i) { float d = v[i] - m; sq = fmaf(d, d, sq); }
  const float rs = rsqrtf(wsum(sq) * (1.0f / 512.0f) + 1e-5f);
  float4 g0 = ((const float4*)g1)[lane], g1v = ((const float4*)g1)[64 + lane];
  float4 c0 = ((const float4*)b1)[lane], c1 = ((const float4*)b1)[64 + lane];
  float4* hp = (float4*)(h + (size_t)row * DD);
  float4 h0 = hp[lane], h1 = hp[64 + lane];
  float a[8];
  a[0] = h0.x + (v[0] - m) * rs * g0.x + c0.x;  a[1] = h0.y + (v[1] - m) * rs * g0.y + c0.y;
  a[2] = h0.z + (v[2] - m) * rs * g0.z + c0.z;  a[3] = h0.w + (v[3] - m) * rs * g0.w + c0.w;
  a[4] = h1.x + (v[4] - m) * rs * g1v.x + c1.x; a[5] = h1.y + (v[5] - m) * rs * g1v.y + c1.y;
  a[6] = h1.z + (v[6] - m) * rs * g1v.z + c1.z; a[7] = h1.w + (v[7] - m) * rs * g1v.w + c1.w;
  hp[lane] = make_float4(a[0], a[1], a[2], a[3]);
  hp[64 + lane] = make_float4(a[4], a[5], a[6], a[7]);
  // second LN
  float s2 = 0.f;
#pragma unroll
  for (int i = 0; i < 8; ++i) s2 += a[i];
  const float m2 = wsum(s2) * (1.0f / 512.0f);
  float sq2 = 0.f;
#pragma unroll
  for (int i = 0; i < 8; ++i) { float d = a[i] - m2; sq2 = fmaf(d, d, sq2); }
  const float rs2 = rsqrtf(wsum(sq2) * (1.0f / 512.0f) + 1e-5f);
  float4 G0 = ((const float4*)g2)[lane], G1 = ((const float4*)g2)[64 + lane];
  float4 B0 = ((const float4*)b2)[lane], B1 = ((const float4*)b2)[64 + lane];
  ushort4 q0, q1;
  q0.x = f2b((a[0] - m2) * rs2 * G0.x + B0.x); q0.y = f2b((a[1] - m2) * rs2 * G0.y + B0.y);
  q0.z = f2b((a[2] - m2) * rs2 * G0.z + B0.z); q0.w = f2b((a[3] - m2) * rs2 * G0.w + B0.w);
  q1.x = f2b((a[4] - m2) * rs2 * G1.x + B1.x); q1.y = f2b((a[5] - m2) * rs2 * G1.y + B1.y);
  q1.z = f2b((a[6] - m2) * rs2 * G1.z + B1.z); q1.w = f2b((a[7] - m2) * rs2 * G1.w + B1.w);
  ushort4* ob = (ushort4*)(xinb + (size_t)row * DD);
  ob[lane] = q0; ob[64 + lane] = q1;
}

// ---------------- generic bf16 MFMA GEMM: C = A[M,K] @ Bt[N,K]^T ----------------
template<int BM, int BN, int WM, int WN, int EPI>
__global__ __launch_bounds__(256) void mgemm(const unsigned short* __restrict__ A,
                                             const unsigned short* __restrict__ Bt,
                                             void* __restrict__ C0, void* __restrict__ C1,
                                             void* __restrict__ C2,
                                             const float* __restrict__ bias,
                                             int M, int N, int K) {
  constexpr int NW = (BM / WM) * (BN / WN);
  constexpr int FM = WM / 16, FN = WN / 16;
  __shared__ char smem[(BM + BN) * 128];
  char* sA = smem; char* sB = smem + BM * 128;
  const int tid = threadIdx.x, lane = tid & 63, wid = tid >> 6;
  const int row0 = blockIdx.y * BM, col0 = blockIdx.x * BN;
  const int wrow = (wid / (BN / WN)) * WM, wcol = (wid % (BN / WN)) * WN;
  f32x4 acc[FM][FN] = {};
  const char* Ag = (const char*)(A + (size_t)row0 * K);
  const char* Bg = (const char*)(Bt + (size_t)col0 * K);
  for (int k0 = 0; k0 < K; k0 += 64) {
    __syncthreads();
    stage_rows(sA, Ag + (size_t)k0 * 2, (size_t)K * 2, BM / 8, wid, NW, lane);
    stage_rows(sB, Bg + (size_t)k0 * 2, (size_t)K * 2, BN / 8, wid, NW, lane);
    __syncthreads();
#pragma unroll
    for (int kk = 0; kk < 2; ++kk) {
      bf16x8 af[FM], bfr[FN];
#pragma unroll
      for (int mi = 0; mi < FM; ++mi)
        af[mi] = frag_ld(sA, wrow + mi * 16 + (lane & 15), kk * 4 + (lane >> 4));
#pragma unroll
      for (int ni = 0; ni < FN; ++ni)
        bfr[ni] = frag_ld(sB, wcol + ni * 16 + (lane & 15), kk * 4 + (lane >> 4));
#pragma unroll
      for (int mi = 0; mi < FM; ++mi)
#pragma unroll
        for (int ni = 0; ni < FN; ++ni)
          acc[mi][ni] = __builtin_amdgcn_mfma_f32_16x16x32_bf16(af[mi], bfr[ni], acc[mi][ni], 0, 0, 0);
    }
  }
#pragma unroll
  for (int mi = 0; mi < FM; ++mi)
#pragma unroll
    for (int ni = 0; ni < FN; ++ni) {
      const int colb = col0 + wcol + ni * 16;
      const int col = colb + (lane & 15);
      const int rowb = row0 + wrow + mi * 16 + (lane >> 4) * 4;
      if (EPI == 1 && (colb >> 9) == 2) {      // V segment -> vt[bh][d][t]
        const int cc = col - 1024, hh = cc >> 6, d = cc & 63, b = rowb >> 9, t = rowb & 511;
        ushort4 pk;
        pk.x = f2b(acc[mi][ni][0]); pk.y = f2b(acc[mi][ni][1]);
        pk.z = f2b(acc[mi][ni][2]); pk.w = f2b(acc[mi][ni][3]);
        *(ushort4*)((unsigned short*)C2 + (((size_t)(b * 8 + hh) * 64 + d) << 9) + t) = pk;
      } else {
#pragma unroll
        for (int r = 0; r < 4; ++r) {
          const int row = rowb + r;
          const float v = acc[mi][ni][r];
          if (EPI == 0) {
            ((float*)C0)[(size_t)row * N + col] = v;
          } else if (EPI == 1) {
            if (colb < 512) ((unsigned short*)C0)[(size_t)row * 512 + col] = f2b(v);
            else            ((unsigned short*)C1)[(size_t)row * 512 + (col - 512)] = f2b(v);
          } else if (EPI == 2) {
            ((unsigned short*)C0)[(size_t)row * N + col] = f2b(gelu_f(v + bias[col]));
          } else {
            ((float*)C0)[(size_t)row * N + col] += v + bias[col];
          }
        }
      }
    }
}

// ---------------- fused attention: S=QK^T -> entmax15 -> P@V, one wave = 16 q-rows ----
// grid (TC/64, B*H); block 256 = 4 waves. No __syncthreads; wave-private LDS chunk.
// NOTE: every loop touching acc[] is FULLY unrolled (rule #20: partial unroll ->
// runtime index -> acc spills to scratch; that was R3's 0.5 GB/dispatch regression).
__global__ __launch_bounds__(256, 2) void attn_fused(const unsigned short* __restrict__ q,
                                                     const unsigned short* __restrict__ k,
                                                     const unsigned short* __restrict__ vt,
                                                     const float* __restrict__ padf,
                                                     unsigned short* __restrict__ attnout) {
  __shared__ char sP[4][2048];
  const int bh = blockIdx.y, b = bh >> 3, hh = bh & 7;
  const int wid = threadIdx.x >> 6, lane = threadIdx.x & 63;
  const int q0 = blockIdx.x * 64 + wid * 16;
  const int col16 = lane & 15, g4 = lane >> 4;
  const unsigned short* qb = q + ((size_t)(b * TC + q0)) * DD + hh * HD;
  const unsigned short* kb = k + ((size_t)(b * TC)) * DD + hh * HD;
  const unsigned short* vb = vt + ((size_t)bh * 64) * 512;

  // ---- S = Q K^T : 64 MFMA, operands direct from global (L2-hot) ----
  f32x4 acc[32] = {};
  const unsigned short* qrow = qb + (size_t)col16 * DD + g4 * 8;
  bf16x8 aq0 = *(const bf16x8*)(qrow);
  bf16x8 aq1 = *(const bf16x8*)(qrow + 32);
#pragma unroll
  for (int ni = 0; ni < 32; ++ni) {
    const unsigned short* krow = kb + (size_t)(16 * ni + col16) * DD + g4 * 8;
    bf16x8 b0 = *(const bf16x8*)(krow);
    bf16x8 b1 = *(const bf16x8*)(krow + 32);
    acc[ni] = __builtin_amdgcn_mfma_f32_16x16x32_bf16(aq0, b0, acc[ni], 0, 0, 0);
    acc[ni] = __builtin_amdgcn_mfma_f32_16x16x32_bf16(aq1, b1, acc[ni], 0, 0, 0);
  }

  // ---- scale (/8 /2), key-pad mask, row max ----
  const int btc = b * TC;
  float mx[4] = {-3.4e38f, -3.4e38f, -3.4e38f, -3.4e38f};
#pragma unroll
  for (int ni = 0; ni < 32; ++ni) {
    const float ma = padf[btc + 16 * ni + col16];
#pragma unroll
    for (int r = 0; r < 4; ++r) {
      acc[ni][r] = fmaf(acc[ni][r], 0.0625f, ma);
      mx[r] = fmaxf(mx[r], acc[ni][r]);
    }
  }
#pragma unroll
  for (int r = 0; r < 4; ++r) {
#pragma unroll
    for (int m = 1; m <= 8; m <<= 1) mx[r] = fmaxf(mx[r], __shfl_xor(mx[r], m, 64));
  }
#pragma unroll
  for (int ni = 0; ni < 32; ++ni)
#pragma unroll
    for (int r = 0; r < 4; ++r) acc[ni][r] -= mx[r];

  // ---- Newton on f(tau)=sum relu(v-tau)^2 = 1 (convex, monotone from below) ----
  float tau[4] = {-1.f, -1.f, -1.f, -1.f};
  for (int it = 0; it < 8; ++it) {
    float s1[4] = {0, 0, 0, 0}, s2[4] = {0, 0, 0, 0};
#pragma unroll
    for (int ni = 0; ni < 32; ++ni)
#pragma unroll
      for (int r = 0; r < 4; ++r) {
        const float d = fmaxf(acc[ni][r] - tau[r], 0.f);
        s1[r] += d; s2[r] = fmaf(d, d, s2[r]);
      }
#pragma unroll
    for (int r = 0; r < 4; ++r) {
#pragma unroll
      for (int m = 1; m <= 8; m <<= 1) {
        s1[r] += __shfl_xor(s1[r], m, 64);
        s2[r] += __shfl_xor(s2[r], m, 64);
      }
      tau[r] += (s2[r] - 1.0f) / (2.0f * fmaxf(s1[r], 1e-20f));
    }
  }
  // ---- closed-form tau* over support {v > tau}, then p = relu(v-tau*)^2, renorm ----
  {
    float c1[4] = {0, 0, 0, 0}, s1[4] = {0, 0, 0, 0}, s2[4] = {0, 0, 0, 0};
#pragma unroll
    for (int ni = 0; ni < 32; ++ni)
#pragma unroll
      for (int r = 0; r < 4; ++r) {
        const float vv = acc[ni][r];
        const float msk = (vv > tau[r]) ? 1.0f : 0.0f;
        c1[r] += msk; s1[r] += msk * vv; s2[r] = fmaf(msk * vv, vv, s2[r]);
      }
#pragma unroll
    for (int r = 0; r < 4; ++r) {
#pragma unroll
      for (int m = 1; m <= 8; m <<= 1) {
        c1[r] += __shfl_xor(c1[r], m, 64);
        s1[r] += __shfl_xor(s1[r], m, 64);
        s2[r] += __shfl_xor(s2[r], m, 64);
      }
      const float disc = fmaxf(s1[r] * s1[r] - c1[r] * s2[r] + c1[r], 0.f);
      tau[r] = (s1[r] - sqrtf(disc)) / c1[r];
    }
  }
  float inv[4];
  {
    float ss[4] = {0, 0, 0, 0};
#pragma unroll
    for (int ni = 0; ni < 32; ++ni)
#pragma unroll
      for (int r = 0; r < 4; ++r) {
        const float d = fmaxf(acc[ni][r] - tau[r], 0.f);
        acc[ni][r] = d * d;
        ss[r] = fmaf(d, d, ss[r]);
      }
#pragma unroll
    for (int r = 0; r < 4; ++r) {
#pragma unroll
      for (int m = 1; m <= 8; m <<= 1) ss[r] += __shfl_xor(ss[r], m, 64);
      inv[r] = 1.0f / ss[r];
    }
  }

  // ---- P@V: per 64-key chunk, write P (bf16, swizzled) to wave-private LDS, MFMA ----
  char* myP = sP[wid];
  f32x4 acc2[4] = {};
#pragma unroll
  for (int c = 0; c < 8; ++c) {
#pragma unroll
    for (int nj = 0; nj < 4; ++nj) {
      const int ni = 4 * c + nj;
#pragma unroll
      for (int r = 0; r < 4; ++r) {
        const int lq = g4 * 4 + r;
        const int ck = nj * 16 + col16;
        *(unsigned short*)(myP + lq * 128 + ((((ck >> 3) ^ (lq & 7))) << 4) + ((ck & 7) << 1)) =
            f2b(acc[ni][r] * inv[r]);
      }
    }
#pragma unroll
    for (int kk = 0; kk < 2; ++kk) {
      const bf16x8 pa = frag_ld(myP, col16, kk * 4 + g4);
#pragma unroll
      for (int n2 = 0; n2 < 4; ++n2) {
        const unsigned short* vrow = vb + (size_t)(16 * n2 + col16) * 512 + c * 64 + kk * 32 + g4 * 8;
        acc2[n2] = __builtin_amdgcn_mfma_f32_16x16x32_bf16(pa, *(const bf16x8*)vrow, acc2[n2], 0, 0, 0);
      }
    }
  }
#pragma unroll
  for (int n2 = 0; n2 < 4; ++n2)
#pragma unroll
    for (int r = 0; r < 4; ++r)
      attnout[((size_t)(b * TC + q0 + g4 * 4 + r)) * DD + hh * HD + 16 * n2 + col16] = f2b(acc2[n2][r]);
}

// ---------------- head ----------------
__global__ void head_k(const float* __restrict__ h, const float* __restrict__ w1,
                       const float* __restrict__ b1, const float* __restrict__ w2,
                       const float* __restrict__ b2, float* __restrict__ out) {
  __shared__ float z[BB][HEADH];
  const int tid = threadIdx.x;
  const int b = tid >> 5, j = tid & 31;
  const float* hr = h + (size_t)(b * TC) * DD;
  float s = 0.f;
  for (int kk = 0; kk < DD; ++kk) s = fmaf(hr[kk], w1[kk * HEADH + j], s);
  z[b][j] = fmaxf(s + b1[j], 0.f);
  __syncthreads();
  if (tid < BB) {
    float acc = b2[0];
#pragma unroll
    for (int q2 = 0; q2 < HEADH; ++q2) acc = fmaf(z[tid][q2], w2[q2], acc);
    out[tid] = acc;
  }
}

// ---------------- workspace layout ----------------
#define WS_NEED 58736640ull
static __device__ __align__(256) unsigned char g_fallback_ws[WS_NEED];

extern "C" void kernel_launch(void* const* d_in, const int* in_sizes, int n_in,
                              void* d_out, int out_size, void* d_ws, size_t ws_size,
                              hipStream_t stream) {
  const int*   x     = (const int*)d_in[0];
  const float* etab  = (const float*)d_in[1];
  const float* ptab  = (const float*)d_in[2];
  const float* cls   = (const float*)d_in[3];
  const float* Wq    = (const float*)d_in[4];
  const float* Wk    = (const float*)d_in[5];
  const float* Wv    = (const float*)d_in[6];
  const float* Wo    = (const float*)d_in[7];
  const float* an_g  = (const float*)d_in[8];
  const float* an_b  = (const float*)d_in[9];
  const float* ln1_g = (const float*)d_in[10];
  const float* ln1_b = (const float*)d_in[11];
  const float* ln2_g = (const float*)d_in[12];
  const float* ln2_b = (const float*)d_in[13];
  const float* f1_w  = (const float*)d_in[14];
  const float* f1_b  = (const float*)d_in[15];
  const float* f2_w  = (const float*)d_in[16];
  const float* f2_b  = (const float*)d_in[17];
  const float* h1_w  = (const float*)d_in[18];
  const float* h1_b  = (const float*)d_in[19];
  const float* h2_w  = (const float*)d_in[20];
  const float* h2_b  = (const float*)d_in[21];
  float* out = (float*)d_out;

  void* wsbase = d_ws;
  if (ws_size < WS_NEED) hipGetSymbolAddress(&wsbase, HIP_SYMBOL(g_fallback_ws));
  char* base = (char*)wsbase;
  const size_t MB = 1048576;
  float* h_    = (float*)(base);
  float* xin_  = (float*)(base + 8 * MB);
  float* t_    = (float*)(base + 16 * MB);
  unsigned short* xinb_ = (unsigned short*)(base + 24 * MB);
  unsigned short* q_    = (unsigned short*)(base + 28 * MB);
  unsigned short* k_    = (unsigned short*)(base + 32 * MB);
  unsigned short* vt_   = (unsigned short*)(base + 36 * MB);
  unsigned short* at_   = (unsigned short*)(base + 40 * MB);
  unsigned short* mid_  = (unsigned short*)(base + 44 * MB);
  unsigned short* qkvT_ = (unsigned short*)(base + 46 * MB);
  unsigned short* woT_  = (unsigned short*)(base + 52 * MB);
  unsigned short* f1T_  = (unsigned short*)(base + 54 * MB);
  unsigned short* f2T_  = (unsigned short*)(base + 55 * MB);
  float* padf_ = (float*)(base + 56 * MB);

  wprep<<<dim3(16, 16, 24), 256, 0, stream>>>(Wq, Wk, Wv, Wo, f1_w, f2_w, qkvT_, woT_, f1T_, f2T_);
  embed_k<<<NTOK, 64, 0, stream>>>(x, etab, ptab, cls, h_, padf_);

  for (int l = 0; l < LL; ++l) {
    ln_rows<<<NTOK / 4, 256, 0, stream>>>(h_, xin_, xinb_, ln1_g + l * DD, ln1_b + l * DD);
    mgemm<128, 128, 64, 64, 1><<<dim3(12, 32), 256, 0, stream>>>(
        xinb_, qkvT_ + (size_t)l * 1536 * 512, q_, k_, vt_, nullptr, NTOK, 1536, 512);
    attn_fused<<<dim3(TC / 64, BB * HH), 256, 0, stream>>>(q_, k_, vt_, padf_, at_);
    mgemm<128, 128, 64, 64, 0><<<dim3(4, 32), 256, 0, stream>>>(
        at_, woT_ + (size_t)l * 512 * 512, t_, nullptr, nullptr, nullptr, NTOK, 512, 512);
    resid_ln2<<<NTOK / 4, 256, 0, stream>>>(t_, xin_, h_, an_g + l * DD, an_b + l * DD,
                                            ln2_g + l * DD, ln2_b + l * DD, xinb_);
    mgemm<64, 64, 32, 32, 2><<<dim3(4, 64), 256, 0, stream>>>(
        xinb_, f1T_ + (size_t)l * 256 * 512, mid_, nullptr, nullptr, f1_b + l * FF, NTOK, 256, 512);
    mgemm<64, 128, 32, 64, 3><<<dim3(4, 64), 256, 0, stream>>>(
        mid_, f2T_ + (size_t)l * 512 * 256, h_, nullptr, nullptr, f2_b + l * DD, NTOK, 512, 256);
  }

  head_k<<<1, 256, 0, stream>>>(h_, h1_w, h1_b, h2_w, h2_b, out);
}

// Round 8
// 545.133 us; speedup vs baseline: 1.7602x; 1.1135x over previous
//
#include <hip/hip_runtime.h>
#include <hip/hip_bf16.h>
#include <math.h>

// ---------------- model dims ----------------
#define BB    8
#define TT    511
#define TC    512
#define DD    512
#define HH    8
#define HD    64
#define LL    4
#define FF    256
#define HEADH 32
#define NTOK  (BB*TC)      // 4096

typedef __bf16 bf16x8 __attribute__((ext_vector_type(8)));
typedef float  f32x4  __attribute__((ext_vector_type(4)));

__device__ __forceinline__ unsigned short f2b(float v) {
  __bf16 t = (__bf16)v;
  return __builtin_bit_cast(unsigned short, t);
}
__device__ __forceinline__ float gelu_f(float x) {
  return 0.5f * x * (1.0f + erff(x * 0.7071067811865476f));
}

// ---------------- fast wave reduce (64-lane): DPP + ds_swizzle + readlane ----------------
template<int CTRL>
__device__ __forceinline__ float dppmov(float x) {
  return __builtin_bit_cast(float,
      __builtin_amdgcn_update_dpp(0, __builtin_bit_cast(int, x), CTRL, 0xF, 0xF, true));
}
__device__ __forceinline__ float wsum(float v) {
  v += dppmov<0xB1>(v);
  v += dppmov<0x4E>(v);
  v += dppmov<0x141>(v);
  v += dppmov<0x140>(v);
  v += __builtin_bit_cast(float, __builtin_amdgcn_ds_swizzle(__builtin_bit_cast(int, v), 0x401F));
  float a = __builtin_bit_cast(float, __builtin_amdgcn_readlane(__builtin_bit_cast(int, v), 0));
  float b = __builtin_bit_cast(float, __builtin_amdgcn_readlane(__builtin_bit_cast(int, v), 32));
  return a + b;
}

// ---------------- async global->LDS staging with both-sides XOR swizzle ----------------
// 128B LDS rows, 8x16B slots. Swizzle key row&7 (for row-stride>=... row-major tiles).
__device__ __forceinline__ void stage_rows(char* lds, const char* g, size_t gstride,
                                           int nIss, int wid, int nw, int lane) {
  for (int is = wid; is < nIss; is += nw) {
    const int row = (is << 3) + (lane >> 3);
    const int s = lane & 7;
    const char* gp = g + (size_t)row * gstride + (((s ^ (row & 7))) << 4);
    __builtin_amdgcn_global_load_lds((const __attribute__((address_space(1))) void*)gp,
                                     (__attribute__((address_space(3))) void*)(lds + ((size_t)is << 10)),
                                     16, 0, 0);
  }
}
__device__ __forceinline__ bf16x8 frag_ld(const char* lds, int row, int kslot) {
  return *(const bf16x8*)(lds + row * 128 + ((kslot ^ (row & 7)) << 4));
}
// V variant: linear 64KB copy (gstride=128), swizzle key (row>>3)&7 so that PV reads
// (which fix the 128B-subrow index 'c' and vary d across lanes) spread over 8 slots.
__device__ __forceinline__ void stage_rows_v(char* lds, const char* g,
                                             int nIss, int wid, int nw, int lane) {
  for (int is = wid; is < nIss; is += nw) {
    const int row = (is << 3) + (lane >> 3);
    const int s = lane & 7;
    const char* gp = g + (size_t)row * 128 + (((s ^ (is & 7))) << 4);   // (row>>3)&7 == is&7
    __builtin_amdgcn_global_load_lds((const __attribute__((address_space(1))) void*)gp,
                                     (__attribute__((address_space(3))) void*)(lds + ((size_t)is << 10)),
                                     16, 0, 0);
  }
}
__device__ __forceinline__ bf16x8 frag_ld_v(const char* lds, int row, int kslot) {
  return *(const bf16x8*)(lds + row * 128 + ((kslot ^ ((row >> 3) & 7)) << 4));
}

// ---------------- embed + pad mask (float addend: 0 or -5e8) ----------------
__global__ void embed_k(const int* __restrict__ x, const float* __restrict__ etab,
                        const float* __restrict__ ptab, const float* __restrict__ cls,
                        float* __restrict__ h, float* __restrict__ padf) {
  const int tok = blockIdx.x;
  const int b = tok >> 9, t = tok & 511;
  const int lane = threadIdx.x;
  float4 o0, o1;
  int isPad = 0;
  if (t == 0) {
    o0 = ((const float4*)cls)[lane];
    o1 = ((const float4*)cls)[64 + lane];
  } else {
    const int id = x[b * TT + (t - 1)];
    isPad = (id == 0);
    const float m = isPad ? 0.0f : 1.0f;
    const float4* e  = (const float4*)(etab + (size_t)id * DD);
    const float4* pp = (const float4*)(ptab + (size_t)(t - 1) * DD);
    float4 e0 = e[lane], e1 = e[64 + lane];
    float4 p0 = pp[lane], p1 = pp[64 + lane];
    o0.x = e0.x * m + p0.x; o0.y = e0.y * m + p0.y;
    o0.z = e0.z * m + p0.z; o0.w = e0.w * m + p0.w;
    o1.x = e1.x * m + p1.x; o1.y = e1.y * m + p1.y;
    o1.z = e1.z * m + p1.z; o1.w = e1.w * m + p1.w;
  }
  float4* hp = (float4*)(h + (size_t)tok * DD);
  hp[lane] = o0; hp[64 + lane] = o1;
  if (lane == 0) padf[tok] = isPad ? -5.0e8f : 0.0f;
}

// ---------------- weight transpose + bf16 convert ----------------
__global__ __launch_bounds__(256) void wprep(const float* __restrict__ Wq, const float* __restrict__ Wk,
                                             const float* __restrict__ Wv, const float* __restrict__ Wo,
                                             const float* __restrict__ f1w, const float* __restrict__ f2w,
                                             unsigned short* __restrict__ qkvT, unsigned short* __restrict__ woT,
                                             unsigned short* __restrict__ f1T, unsigned short* __restrict__ f2T) {
  const int z = blockIdx.z;
  const float* src; unsigned short* dst; int K, N;
  if (z < 12) { int l = z / 3, w = z % 3;
    src = (w == 0 ? Wq : w == 1 ? Wk : Wv) + (size_t)l * 512 * 512; K = 512; N = 512;
    dst = qkvT + (size_t)l * 1536 * 512 + (size_t)w * 512 * 512;
  } else if (z < 16) { int l = z - 12; src = Wo + (size_t)l * 512 * 512; K = 512; N = 512;
    dst = woT + (size_t)l * 512 * 512;
  } else if (z < 20) { int l = z - 16; src = f1w + (size_t)l * 512 * 256; K = 512; N = 256;
    dst = f1T + (size_t)l * 256 * 512;
  } else { int l = z - 20; src = f2w + (size_t)l * 256 * 512; K = 256; N = 512;
    dst = f2T + (size_t)l * 512 * 256;
  }
  const int n0 = blockIdx.x * 32, k0 = blockIdx.y * 32;
  if (n0 >= N || k0 >= K) return;
  __shared__ float tbuf[32][33];
  const int tx = threadIdx.x & 31, ty = threadIdx.x >> 5;
#pragma unroll
  for (int i = 0; i < 32; i += 8)
    tbuf[ty + i][tx] = src[(size_t)(k0 + ty + i) * N + n0 + tx];
  __syncthreads();
#pragma unroll
  for (int i = 0; i < 32; i += 8)
    dst[(size_t)(n0 + ty + i) * K + k0 + tx] = f2b(tbuf[tx][ty + i]);
}

// ---------------- layernorm: f32 out + bf16 out ----------------
__global__ __launch_bounds__(256) void ln_rows(const float* __restrict__ in,
                                               float* __restrict__ outf,
                                               unsigned short* __restrict__ outb,
                                               const float* __restrict__ g,
                                               const float* __restrict__ b) {
  const int wave = threadIdx.x >> 6, lane = threadIdx.x & 63;
  const int row = blockIdx.x * 4 + wave;
  const float* p = in + (size_t)row * DD;
  float4 a = ((const float4*)p)[lane];
  float4 c = ((const float4*)p)[64 + lane];
  float v[8] = {a.x, a.y, a.z, a.w, c.x, c.y, c.z, c.w};
  float s = 0.f;
#pragma unroll
  for (int i = 0; i < 8; ++i) s += v[i];
  const float m = wsum(s) * (1.0f / 512.0f);
  float sq = 0.f;
#pragma unroll
  for (int i = 0; i < 8; ++i) { float d = v[i] - m; sq = fmaf(d, d, sq); }
  const float rs = rsqrtf(wsum(sq) * (1.0f / 512.0f) + 1e-5f);
  float4 g0 = ((const float4*)g)[lane], g1 = ((const float4*)g)[64 + lane];
  float4 b0 = ((const float4*)b)[lane], b1 = ((const float4*)b)[64 + lane];
  float r[8];
  r[0] = (v[0] - m) * rs * g0.x + b0.x; r[1] = (v[1] - m) * rs * g0.y + b0.y;
  r[2] = (v[2] - m) * rs * g0.z + b0.z; r[3] = (v[3] - m) * rs * g0.w + b0.w;
  r[4] = (v[4] - m) * rs * g1.x + b1.x; r[5] = (v[5] - m) * rs * g1.y + b1.y;
  r[6] = (v[6] - m) * rs * g1.z + b1.z; r[7] = (v[7] - m) * rs * g1.w + b1.w;
  float4* op = (float4*)(outf + (size_t)row * DD);
  op[lane] = make_float4(r[0], r[1], r[2], r[3]);
  op[64 + lane] = make_float4(r[4], r[5], r[6], r[7]);
  ushort4 q0, q1;
  q0.x = f2b(r[0]); q0.y = f2b(r[1]); q0.z = f2b(r[2]); q0.w = f2b(r[3]);
  q1.x = f2b(r[4]); q1.y = f2b(r[5]); q1.z = f2b(r[6]); q1.w = f2b(r[7]);
  ushort4* ob = (ushort4*)(outb + (size_t)row * DD);
  ob[lane] = q0; ob[64 + lane] = q1;
}

// h = LN1(t + xin)*g1 + b1 + h ; then xinb = bf16(LN2(h)*g2 + b2)
__global__ __launch_bounds__(256) void resid_ln2(const float* __restrict__ t,
                                                 const float* __restrict__ xin,
                                                 float* __restrict__ h,
                                                 const float* __restrict__ g1,
                                                 const float* __restrict__ b1,
                                                 const float* __restrict__ g2,
                                                 const float* __restrict__ b2,
                                                 unsigned short* __restrict__ xinb) {
  const int wave = threadIdx.x >> 6, lane = threadIdx.x & 63;
  const int row = blockIdx.x * 4 + wave;
  const float* tp = t + (size_t)row * DD;
  const float* xp = xin + (size_t)row * DD;
  float4 t0 = ((const float4*)tp)[lane], t1 = ((const float4*)tp)[64 + lane];
  float4 x0 = ((const float4*)xp)[lane], x1 = ((const float4*)xp)[64 + lane];
  float v[8] = {t0.x + x0.x, t0.y + x0.y, t0.z + x0.z, t0.w + x0.w,
                t1.x + x1.x, t1.y + x1.y, t1.z + x1.z, t1.w + x1.w};
  float s = 0.f;
#pragma unroll
  for (int i = 0; i < 8; ++i) s += v[i];
  const float m = wsum(s) * (1.0f / 512.0f);
  float sq = 0.f;
#pragma unroll
  for (int i = 0; i < 8; ++i) { float d = v[i] - m; sq = fmaf(d, d, sq); }
  const float rs = rsqrtf(wsum(sq) * (1.0f / 512.0f) + 1e-5f);
  float4 g0 = ((const float4*)g1)[lane], g1v = ((const float4*)g1)[64 + lane];
  float4 c0 = ((const float4*)b1)[lane], c1 = ((const float4*)b1)[64 + lane];
  float4* hp = (float4*)(h + (size_t)row * DD);
  float4 h0 = hp[lane], h1 = hp[64 + lane];
  float a[8];
  a[0] = h0.x + (v[0] - m) * rs * g0.x + c0.x;  a[1] = h0.y + (v[1] - m) * rs * g0.y + c0.y;
  a[2] = h0.z + (v[2] - m) * rs * g0.z + c0.z;  a[3] = h0.w + (v[3] - m) * rs * g0.w + c0.w;
  a[4] = h1.x + (v[4] - m) * rs * g1v.x + c1.x; a[5] = h1.y + (v[5] - m) * rs * g1v.y + c1.y;
  a[6] = h1.z + (v[6] - m) * rs * g1v.z + c1.z; a[7] = h1.w + (v[7] - m) * rs * g1v.w + c1.w;
  hp[lane] = make_float4(a[0], a[1], a[2], a[3]);
  hp[64 + lane] = make_float4(a[4], a[5], a[6], a[7]);
  // second LN
  float s2 = 0.f;
#pragma unroll
  for (int i = 0; i < 8; ++i) s2 += a[i];
  const float m2 = wsum(s2) * (1.0f / 512.0f);
  float sq2 = 0.f;
#pragma unroll
  for (int i = 0; i < 8; ++i) { float d = a[i] - m2; sq2 = fmaf(d, d, sq2); }
  const float rs2 = rsqrtf(wsum(sq2) * (1.0f / 512.0f) + 1e-5f);
  float4 G0 = ((const float4*)g2)[lane], G1 = ((const float4*)g2)[64 + lane];
  float4 B0 = ((const float4*)b2)[lane], B1 = ((const float4*)b2)[64 + lane];
  ushort4 q0, q1;
  q0.x = f2b((a[0] - m2) * rs2 * G0.x + B0.x); q0.y = f2b((a[1] - m2) * rs2 * G0.y + B0.y);
  q0.z = f2b((a[2] - m2) * rs2 * G0.z + B0.z); q0.w = f2b((a[3] - m2) * rs2 * G0.w + B0.w);
  q1.x = f2b((a[4] - m2) * rs2 * G1.x + B1.x); q1.y = f2b((a[5] - m2) * rs2 * G1.y + B1.y);
  q1.z = f2b((a[6] - m2) * rs2 * G1.z + B1.z); q1.w = f2b((a[7] - m2) * rs2 * G1.w + B1.w);
  ushort4* ob = (ushort4*)(xinb + (size_t)row * DD);
  ob[lane] = q0; ob[64 + lane] = q1;
}

// ---------------- generic bf16 MFMA GEMM: C = A[M,K] @ Bt[N,K]^T ----------------
template<int BM, int BN, int WM, int WN, int EPI>
__global__ __launch_bounds__(256) void mgemm(const unsigned short* __restrict__ A,
                                             const unsigned short* __restrict__ Bt,
                                             void* __restrict__ C0, void* __restrict__ C1,
                                             void* __restrict__ C2,
                                             const float* __restrict__ bias,
                                             int M, int N, int K) {
  constexpr int NW = (BM / WM) * (BN / WN);
  constexpr int FM = WM / 16, FN = WN / 16;
  __shared__ char smem[(BM + BN) * 128];
  char* sA = smem; char* sB = smem + BM * 128;
  const int tid = threadIdx.x, lane = tid & 63, wid = tid >> 6;
  const int row0 = blockIdx.y * BM, col0 = blockIdx.x * BN;
  const int wrow = (wid / (BN / WN)) * WM, wcol = (wid % (BN / WN)) * WN;
  f32x4 acc[FM][FN] = {};
  const char* Ag = (const char*)(A + (size_t)row0 * K);
  const char* Bg = (const char*)(Bt + (size_t)col0 * K);
  for (int k0 = 0; k0 < K; k0 += 64) {
    __syncthreads();
    stage_rows(sA, Ag + (size_t)k0 * 2, (size_t)K * 2, BM / 8, wid, NW, lane);
    stage_rows(sB, Bg + (size_t)k0 * 2, (size_t)K * 2, BN / 8, wid, NW, lane);
    __syncthreads();
#pragma unroll
    for (int kk = 0; kk < 2; ++kk) {
      bf16x8 af[FM], bfr[FN];
#pragma unroll
      for (int mi = 0; mi < FM; ++mi)
        af[mi] = frag_ld(sA, wrow + mi * 16 + (lane & 15), kk * 4 + (lane >> 4));
#pragma unroll
      for (int ni = 0; ni < FN; ++ni)
        bfr[ni] = frag_ld(sB, wcol + ni * 16 + (lane & 15), kk * 4 + (lane >> 4));
#pragma unroll
      for (int mi = 0; mi < FM; ++mi)
#pragma unroll
        for (int ni = 0; ni < FN; ++ni)
          acc[mi][ni] = __builtin_amdgcn_mfma_f32_16x16x32_bf16(af[mi], bfr[ni], acc[mi][ni], 0, 0, 0);
    }
  }
#pragma unroll
  for (int mi = 0; mi < FM; ++mi)
#pragma unroll
    for (int ni = 0; ni < FN; ++ni) {
      const int colb = col0 + wcol + ni * 16;
      const int col = colb + (lane & 15);
      const int rowb = row0 + wrow + mi * 16 + (lane >> 4) * 4;
      if (EPI == 1 && (colb >> 9) == 2) {      // V segment -> vt[bh][d][t]
        const int cc = col - 1024, hh = cc >> 6, d = cc & 63, b = rowb >> 9, t = rowb & 511;
        ushort4 pk;
        pk.x = f2b(acc[mi][ni][0]); pk.y = f2b(acc[mi][ni][1]);
        pk.z = f2b(acc[mi][ni][2]); pk.w = f2b(acc[mi][ni][3]);
        *(ushort4*)((unsigned short*)C2 + (((size_t)(b * 8 + hh) * 64 + d) << 9) + t) = pk;
      } else {
#pragma unroll
        for (int r = 0; r < 4; ++r) {
          const int row = rowb + r;
          const float v = acc[mi][ni][r];
          if (EPI == 0) {
            ((float*)C0)[(size_t)row * N + col] = v;
          } else if (EPI == 1) {
            if (colb < 512) ((unsigned short*)C0)[(size_t)row * 512 + col] = f2b(v);
            else            ((unsigned short*)C1)[(size_t)row * 512 + (col - 512)] = f2b(v);
          } else if (EPI == 2) {
            ((unsigned short*)C0)[(size_t)row * N + col] = f2b(gelu_f(v + bias[col]));
          } else {
            ((float*)C0)[(size_t)row * N + col] += v + bias[col];
          }
        }
      }
    }
}

// ---------------- fused attention: S=QK^T -> entmax15 -> P@V, one wave = 16 q-rows ----
// grid (TC/64, B*H); block 256 = 4 waves. K staged in LDS once per block; the same
// 64KB buffer is re-staged with V during entmax (async load hidden under VALU work).
// All acc[] loops FULLY unrolled (rule #20).
__global__ __launch_bounds__(256, 2) void attn_fused(const unsigned short* __restrict__ q,
                                                     const unsigned short* __restrict__ k,
                                                     const unsigned short* __restrict__ vt,
                                                     const float* __restrict__ padf,
                                                     unsigned short* __restrict__ attnout) {
  __shared__ char sKV[65536];
  __shared__ char sP[4][2048];
  const int bh = blockIdx.y, b = bh >> 3, hh = bh & 7;
  const int wid = threadIdx.x >> 6, lane = threadIdx.x & 63;
  const int q0 = blockIdx.x * 64 + wid * 16;
  const int col16 = lane & 15, g4 = lane >> 4;
  const unsigned short* qb = q + ((size_t)(b * TC + q0)) * DD + hh * HD;
  const unsigned short* kb = k + ((size_t)(b * TC)) * DD + hh * HD;
  const unsigned short* vb = vt + ((size_t)bh * 64) * 512;

  // ---- stage K slice [512 tok][64 d] (128B rows, stride 1024B) into LDS ----
  stage_rows(sKV, (const char*)kb, 1024, 64, wid, 4, lane);
  const unsigned short* qrow = qb + (size_t)col16 * DD + g4 * 8;
  bf16x8 aq0 = *(const bf16x8*)(qrow);
  bf16x8 aq1 = *(const bf16x8*)(qrow + 32);
  __syncthreads();   // drains vmcnt -> K resident

  // ---- S = Q K^T : 64 MFMA from LDS ----
  f32x4 acc[32] = {};
#pragma unroll
  for (int ni = 0; ni < 32; ++ni) {
    const int krow = 16 * ni + col16;
    bf16x8 b0 = frag_ld(sKV, krow, g4);
    bf16x8 b1 = frag_ld(sKV, krow, 4 + g4);
    acc[ni] = __builtin_amdgcn_mfma_f32_16x16x32_bf16(aq0, b0, acc[ni], 0, 0, 0);
    acc[ni] = __builtin_amdgcn_mfma_f32_16x16x32_bf16(aq1, b1, acc[ni], 0, 0, 0);
  }
  __syncthreads();   // all waves done reading K from LDS

  // ---- stage V slice (64KB linear) into the same buffer; entmax runs under it ----
  stage_rows_v(sKV, (const char*)vb, 64, wid, 4, lane);

  // ---- scale (/8 /2), key-pad mask, row max (UNSHIFTED; tau is absolute) ----
  const int btc = b * TC;
  float mx[4] = {-3.4e38f, -3.4e38f, -3.4e38f, -3.4e38f};
#pragma unroll
  for (int ni = 0; ni < 32; ++ni) {
    const float ma = padf[btc + 16 * ni + col16];
#pragma unroll
    for (int r = 0; r < 4; ++r) {
      acc[ni][r] = fmaf(acc[ni][r], 0.0625f, ma);
      mx[r] = fmaxf(mx[r], acc[ni][r]);
    }
  }
#pragma unroll
  for (int r = 0; r < 4; ++r) {
#pragma unroll
    for (int m = 1; m <= 8; m <<= 1) mx[r] = fmaxf(mx[r], __shfl_xor(mx[r], m, 64));
  }

  // ---- Newton on f(tau)=sum relu(v-tau)^2 = 1, tau0 = mx-1 (converges from below) ----
  float tau[4] = {mx[0] - 1.f, mx[1] - 1.f, mx[2] - 1.f, mx[3] - 1.f};
  for (int it = 0; it < 6; ++it) {
    float s1[4] = {0, 0, 0, 0}, s2[4] = {0, 0, 0, 0};
#pragma unroll
    for (int ni = 0; ni < 32; ++ni)
#pragma unroll
      for (int r = 0; r < 4; ++r) {
        const float d = fmaxf(acc[ni][r] - tau[r], 0.f);
        s1[r] += d; s2[r] = fmaf(d, d, s2[r]);
      }
#pragma unroll
    for (int r = 0; r < 4; ++r) {
#pragma unroll
      for (int m = 1; m <= 8; m <<= 1) {
        s1[r] += __shfl_xor(s1[r], m, 64);
        s2[r] += __shfl_xor(s2[r], m, 64);
      }
      tau[r] += (s2[r] - 1.0f) / (2.0f * fmaxf(s1[r], 1e-20f));
    }
  }
  // ---- closed-form tau* over support {v > tau} (shift-invariant formula) ----
  {
    float c1[4] = {0, 0, 0, 0}, s1[4] = {0, 0, 0, 0}, s2[4] = {0, 0, 0, 0};
#pragma unroll
    for (int ni = 0; ni < 32; ++ni)
#pragma unroll
      for (int r = 0; r < 4; ++r) {
        const float vv = acc[ni][r];
        const float msk = (vv > tau[r]) ? 1.0f : 0.0f;
        c1[r] += msk; s1[r] += msk * vv; s2[r] = fmaf(msk * vv, vv, s2[r]);
      }
#pragma unroll
    for (int r = 0; r < 4; ++r) {
#pragma unroll
      for (int m = 1; m <= 8; m <<= 1) {
        c1[r] += __shfl_xor(c1[r], m, 64);
        s1[r] += __shfl_xor(s1[r], m, 64);
        s2[r] += __shfl_xor(s2[r], m, 64);
      }
      const float disc = fmaxf(s1[r] * s1[r] - c1[r] * s2[r] + c1[r], 0.f);
      tau[r] = (s1[r] - sqrtf(disc)) / c1[r];
    }
  }
  float inv[4];
  {
    float ss[4] = {0, 0, 0, 0};
#pragma unroll
    for (int ni = 0; ni < 32; ++ni)
#pragma unroll
      for (int r = 0; r < 4; ++r) {
        const float d = fmaxf(acc[ni][r] - tau[r], 0.f);
        acc[ni][r] = d * d;
        ss[r] = fmaf(d, d, ss[r]);
      }
#pragma unroll
    for (int r = 0; r < 4; ++r) {
#pragma unroll
      for (int m = 1; m <= 8; m <<= 1) ss[r] += __shfl_xor(ss[r], m, 64);
      inv[r] = 1.0f / ss[r];
    }
  }
  __syncthreads();   // drains vmcnt -> V resident in sKV

  // ---- P@V: per 64-key chunk, write P (bf16, swizzled) to wave-private LDS, MFMA ----
  char* myP = sP[wid];
  f32x4 acc2[4] = {};
#pragma unroll
  for (int c = 0; c < 8; ++c) {
#pragma unroll
    for (int nj = 0; nj < 4; ++nj) {
      const int ni = 4 * c + nj;
#pragma unroll
      for (int r = 0; r < 4; ++r) {
        const int lq = g4 * 4 + r;
        const int ck = nj * 16 + col16;
        *(unsigned short*)(myP + lq * 128 + ((((ck >> 3) ^ (lq & 7))) << 4) + ((ck & 7) << 1)) =
            f2b(acc[ni][r] * inv[r]);
      }
    }
#pragma unroll
    for (int kk = 0; kk < 2; ++kk) {
      const bf16x8 pa = frag_ld(myP, col16, kk * 4 + g4);
#pragma unroll
      for (int n2 = 0; n2 < 4; ++n2) {
        // V fragment: d-row (16*n2+col16), key cols c*64+kk*32+g4*8 -> 128B-row d*8+c
        const bf16x8 vv = frag_ld_v(sKV, (16 * n2 + col16) * 8 + c, kk * 4 + g4);
        acc2[n2] = __builtin_amdgcn_mfma_f32_16x16x32_bf16(pa, vv, acc2[n2], 0, 0, 0);
      }
    }
  }
#pragma unroll
  for (int n2 = 0; n2 < 4; ++n2)
#pragma unroll
    for (int r = 0; r < 4; ++r)
      attnout[((size_t)(b * TC + q0 + g4 * 4 + r)) * DD + hh * HD + 16 * n2 + col16] = f2b(acc2[n2][r]);
}

// ---------------- head ----------------
__global__ void head_k(const float* __restrict__ h, const float* __restrict__ w1,
                       const float* __restrict__ b1, const float* __restrict__ w2,
                       const float* __restrict__ b2, float* __restrict__ out) {
  __shared__ float z[BB][HEADH];
  const int tid = threadIdx.x;
  const int b = tid >> 5, j = tid & 31;
  const float* hr = h + (size_t)(b * TC) * DD;
  float s = 0.f;
  for (int kk = 0; kk < DD; ++kk) s = fmaf(hr[kk], w1[kk * HEADH + j], s);
  z[b][j] = fmaxf(s + b1[j], 0.f);
  __syncthreads();
  if (tid < BB) {
    float acc = b2[0];
#pragma unroll
    for (int q2 = 0; q2 < HEADH; ++q2) acc = fmaf(z[tid][q2], w2[q2], acc);
    out[tid] = acc;
  }
}

// ---------------- workspace layout ----------------
#define WS_NEED 58736640ull
static __device__ __align__(256) unsigned char g_fallback_ws[WS_NEED];

extern "C" void kernel_launch(void* const* d_in, const int* in_sizes, int n_in,
                              void* d_out, int out_size, void* d_ws, size_t ws_size,
                              hipStream_t stream) {
  const int*   x     = (const int*)d_in[0];
  const float* etab  = (const float*)d_in[1];
  const float* ptab  = (const float*)d_in[2];
  const float* cls   = (const float*)d_in[3];
  const float* Wq    = (const float*)d_in[4];
  const float* Wk    = (const float*)d_in[5];
  const float* Wv    = (const float*)d_in[6];
  const float* Wo    = (const float*)d_in[7];
  const float* an_g  = (const float*)d_in[8];
  const float* an_b  = (const float*)d_in[9];
  const float* ln1_g = (const float*)d_in[10];
  const float* ln1_b = (const float*)d_in[11];
  const float* ln2_g = (const float*)d_in[12];
  const float* ln2_b = (const float*)d_in[13];
  const float* f1_w  = (const float*)d_in[14];
  const float* f1_b  = (const float*)d_in[15];
  const float* f2_w  = (const float*)d_in[16];
  const float* f2_b  = (const float*)d_in[17];
  const float* h1_w  = (const float*)d_in[18];
  const float* h1_b  = (const float*)d_in[19];
  const float* h2_w  = (const float*)d_in[20];
  const float* h2_b  = (const float*)d_in[21];
  float* out = (float*)d_out;

  void* wsbase = d_ws;
  if (ws_size < WS_NEED) hipGetSymbolAddress(&wsbase, HIP_SYMBOL(g_fallback_ws));
  char* base = (char*)wsbase;
  const size_t MB = 1048576;
  float* h_    = (float*)(base);
  float* xin_  = (float*)(base + 8 * MB);
  float* t_    = (float*)(base + 16 * MB);
  unsigned short* xinb_ = (unsigned short*)(base + 24 * MB);
  unsigned short* q_    = (unsigned short*)(base + 28 * MB);
  unsigned short* k_    = (unsigned short*)(base + 32 * MB);
  unsigned short* vt_   = (unsigned short*)(base + 36 * MB);
  unsigned short* at_   = (unsigned short*)(base + 40 * MB);
  unsigned short* mid_  = (unsigned short*)(base + 44 * MB);
  unsigned short* qkvT_ = (unsigned short*)(base + 46 * MB);
  unsigned short* woT_  = (unsigned short*)(base + 52 * MB);
  unsigned short* f1T_  = (unsigned short*)(base + 54 * MB);
  unsigned short* f2T_  = (unsigned short*)(base + 55 * MB);
  float* padf_ = (float*)(base + 56 * MB);

  wprep<<<dim3(16, 16, 24), 256, 0, stream>>>(Wq, Wk, Wv, Wo, f1_w, f2_w, qkvT_, woT_, f1T_, f2T_);
  embed_k<<<NTOK, 64, 0, stream>>>(x, etab, ptab, cls, h_, padf_);

  for (int l = 0; l < LL; ++l) {
    ln_rows<<<NTOK / 4, 256, 0, stream>>>(h_, xin_, xinb_, ln1_g + l * DD, ln1_b + l * DD);
    mgemm<128, 128, 64, 64, 1><<<dim3(12, 32), 256, 0, stream>>>(
        xinb_, qkvT_ + (size_t)l * 1536 * 512, q_, k_, vt_, nullptr, NTOK, 1536, 512);
    attn_fused<<<dim3(TC / 64, BB * HH), 256, 0, stream>>>(q_, k_, vt_, padf_, at_);
    mgemm<128, 128, 64, 64, 0><<<dim3(4, 32), 256, 0, stream>>>(
        at_, woT_ + (size_t)l * 512 * 512, t_, nullptr, nullptr, nullptr, NTOK, 512, 512);
    resid_ln2<<<NTOK / 4, 256, 0, stream>>>(t_, xin_, h_, an_g + l * DD, an_b + l * DD,
                                            ln2_g + l * DD, ln2_b + l * DD, xinb_);
    mgemm<64, 64, 32, 32, 2><<<dim3(4, 64), 256, 0, stream>>>(
        xinb_, f1T_ + (size_t)l * 256 * 512, mid_, nullptr, nullptr, f1_b + l * FF, NTOK, 256, 512);
    mgemm<64, 128, 32, 64, 3><<<dim3(4, 64), 256, 0, stream>>>(
        mid_, f2T_ + (size_t)l * 512 * 256, h_, nullptr, nullptr, f2_b + l * DD, NTOK, 512, 256);
  }

  head_k<<<1, 256, 0, stream>>>(h_, h1_w, h1_b, h2_w, h2_b, out);
}

// Round 9
// 495.702 us; speedup vs baseline: 1.9357x; 1.0997x over previous
//
#include <hip/hip_runtime.h>
#include <hip/hip_bf16.h>
#include <math.h>

// ---------------- model dims ----------------
#define BB    8
#define TT    511
#define TC    512
#define DD    512
#define HH    8
#define HD    64
#define LL    4
#define FF    256
#define HEADH 32
#define NTOK  (BB*TC)      // 4096

typedef __bf16 bf16x8 __attribute__((ext_vector_type(8)));
typedef float  f32x4  __attribute__((ext_vector_type(4)));

__device__ __forceinline__ unsigned short f2b(float v) {
  __bf16 t = (__bf16)v;
  return __builtin_bit_cast(unsigned short, t);
}
__device__ __forceinline__ float gelu_f(float x) {
  return 0.5f * x * (1.0f + erff(x * 0.7071067811865476f));
}

// ---------------- fast wave reduce (64-lane): DPP + ds_swizzle + readlane ----------------
template<int CTRL>
__device__ __forceinline__ float dppmov(float x) {
  return __builtin_bit_cast(float,
      __builtin_amdgcn_update_dpp(0, __builtin_bit_cast(int, x), CTRL, 0xF, 0xF, true));
}
__device__ __forceinline__ float wsum(float v) {
  v += dppmov<0xB1>(v);
  v += dppmov<0x4E>(v);
  v += dppmov<0x141>(v);
  v += dppmov<0x140>(v);
  v += __builtin_bit_cast(float, __builtin_amdgcn_ds_swizzle(__builtin_bit_cast(int, v), 0x401F));
  float a = __builtin_bit_cast(float, __builtin_amdgcn_readlane(__builtin_bit_cast(int, v), 0));
  float b = __builtin_bit_cast(float, __builtin_amdgcn_readlane(__builtin_bit_cast(int, v), 32));
  return a + b;
}

// ---------------- async global->LDS staging with both-sides XOR swizzle ----------------
// 128B LDS rows, 8x16B slots. Swizzle key row&7.
__device__ __forceinline__ void stage_rows(char* lds, const char* g, size_t gstride,
                                           int nIss, int wid, int nw, int lane) {
  for (int is = wid; is < nIss; is += nw) {
    const int row = (is << 3) + (lane >> 3);
    const int s = lane & 7;
    const char* gp = g + (size_t)row * gstride + (((s ^ (row & 7))) << 4);
    __builtin_amdgcn_global_load_lds((const __attribute__((address_space(1))) void*)gp,
                                     (__attribute__((address_space(3))) void*)(lds + ((size_t)is << 10)),
                                     16, 0, 0);
  }
}
__device__ __forceinline__ bf16x8 frag_ld(const char* lds, int row, int kslot) {
  return *(const bf16x8*)(lds + row * 128 + ((kslot ^ (row & 7)) << 4));
}
// V variant: linear 64KB copy (gstride=128), swizzle key (row>>3)&7 so PV reads
// (fixed 128B-subrow 'c', d varying across lanes) spread over 8 slots.
__device__ __forceinline__ void stage_rows_v(char* lds, const char* g,
                                             int nIss, int wid, int nw, int lane) {
  for (int is = wid; is < nIss; is += nw) {
    const int row = (is << 3) + (lane >> 3);
    const int s = lane & 7;
    const char* gp = g + (size_t)row * 128 + (((s ^ (is & 7))) << 4);   // (row>>3)&7 == is&7
    __builtin_amdgcn_global_load_lds((const __attribute__((address_space(1))) void*)gp,
                                     (__attribute__((address_space(3))) void*)(lds + ((size_t)is << 10)),
                                     16, 0, 0);
  }
}
__device__ __forceinline__ bf16x8 frag_ld_v(const char* lds, int row, int kslot) {
  return *(const bf16x8*)(lds + row * 128 + ((kslot ^ ((row >> 3) & 7)) << 4));
}

// ---------------- embed + pad mask (float addend: 0 or -5e8) ----------------
__global__ void embed_k(const int* __restrict__ x, const float* __restrict__ etab,
                        const float* __restrict__ ptab, const float* __restrict__ cls,
                        float* __restrict__ h, float* __restrict__ padf) {
  const int tok = blockIdx.x;
  const int b = tok >> 9, t = tok & 511;
  const int lane = threadIdx.x;
  float4 o0, o1;
  int isPad = 0;
  if (t == 0) {
    o0 = ((const float4*)cls)[lane];
    o1 = ((const float4*)cls)[64 + lane];
  } else {
    const int id = x[b * TT + (t - 1)];
    isPad = (id == 0);
    const float m = isPad ? 0.0f : 1.0f;
    const float4* e  = (const float4*)(etab + (size_t)id * DD);
    const float4* pp = (const float4*)(ptab + (size_t)(t - 1) * DD);
    float4 e0 = e[lane], e1 = e[64 + lane];
    float4 p0 = pp[lane], p1 = pp[64 + lane];
    o0.x = e0.x * m + p0.x; o0.y = e0.y * m + p0.y;
    o0.z = e0.z * m + p0.z; o0.w = e0.w * m + p0.w;
    o1.x = e1.x * m + p1.x; o1.y = e1.y * m + p1.y;
    o1.z = e1.z * m + p1.z; o1.w = e1.w * m + p1.w;
  }
  float4* hp = (float4*)(h + (size_t)tok * DD);
  hp[lane] = o0; hp[64 + lane] = o1;
  if (lane == 0) padf[tok] = isPad ? -5.0e8f : 0.0f;
}

// ---------------- weight transpose + bf16 convert ----------------
__global__ __launch_bounds__(256) void wprep(const float* __restrict__ Wq, const float* __restrict__ Wk,
                                             const float* __restrict__ Wv, const float* __restrict__ Wo,
                                             const float* __restrict__ f1w, const float* __restrict__ f2w,
                                             unsigned short* __restrict__ qkvT, unsigned short* __restrict__ woT,
                                             unsigned short* __restrict__ f1T, unsigned short* __restrict__ f2T) {
  const int z = blockIdx.z;
  const float* src; unsigned short* dst; int K, N;
  if (z < 12) { int l = z / 3, w = z % 3;
    src = (w == 0 ? Wq : w == 1 ? Wk : Wv) + (size_t)l * 512 * 512; K = 512; N = 512;
    dst = qkvT + (size_t)l * 1536 * 512 + (size_t)w * 512 * 512;
  } else if (z < 16) { int l = z - 12; src = Wo + (size_t)l * 512 * 512; K = 512; N = 512;
    dst = woT + (size_t)l * 512 * 512;
  } else if (z < 20) { int l = z - 16; src = f1w + (size_t)l * 512 * 256; K = 512; N = 256;
    dst = f1T + (size_t)l * 256 * 512;
  } else { int l = z - 20; src = f2w + (size_t)l * 256 * 512; K = 256; N = 512;
    dst = f2T + (size_t)l * 512 * 256;
  }
  const int n0 = blockIdx.x * 32, k0 = blockIdx.y * 32;
  if (n0 >= N || k0 >= K) return;
  __shared__ float tbuf[32][33];
  const int tx = threadIdx.x & 31, ty = threadIdx.x >> 5;
#pragma unroll
  for (int i = 0; i < 32; i += 8)
    tbuf[ty + i][tx] = src[(size_t)(k0 + ty + i) * N + n0 + tx];
  __syncthreads();
#pragma unroll
  for (int i = 0; i < 32; i += 8)
    dst[(size_t)(n0 + ty + i) * K + k0 + tx] = f2b(tbuf[tx][ty + i]);
}

// ---------------- layernorm: f32 out + bf16 out ----------------
__global__ __launch_bounds__(256) void ln_rows(const float* __restrict__ in,
                                               float* __restrict__ outf,
                                               unsigned short* __restrict__ outb,
                                               const float* __restrict__ g,
                                               const float* __restrict__ b) {
  const int wave = threadIdx.x >> 6, lane = threadIdx.x & 63;
  const int row = blockIdx.x * 4 + wave;
  const float* p = in + (size_t)row * DD;
  float4 a = ((const float4*)p)[lane];
  float4 c = ((const float4*)p)[64 + lane];
  float v[8] = {a.x, a.y, a.z, a.w, c.x, c.y, c.z, c.w};
  float s = 0.f;
#pragma unroll
  for (int i = 0; i < 8; ++i) s += v[i];
  const float m = wsum(s) * (1.0f / 512.0f);
  float sq = 0.f;
#pragma unroll
  for (int i = 0; i < 8; ++i) { float d = v[i] - m; sq = fmaf(d, d, sq); }
  const float rs = rsqrtf(wsum(sq) * (1.0f / 512.0f) + 1e-5f);
  float4 g0 = ((const float4*)g)[lane], g1 = ((const float4*)g)[64 + lane];
  float4 b0 = ((const float4*)b)[lane], b1 = ((const float4*)b)[64 + lane];
  float r[8];
  r[0] = (v[0] - m) * rs * g0.x + b0.x; r[1] = (v[1] - m) * rs * g0.y + b0.y;
  r[2] = (v[2] - m) * rs * g0.z + b0.z; r[3] = (v[3] - m) * rs * g0.w + b0.w;
  r[4] = (v[4] - m) * rs * g1.x + b1.x; r[5] = (v[5] - m) * rs * g1.y + b1.y;
  r[6] = (v[6] - m) * rs * g1.z + b1.z; r[7] = (v[7] - m) * rs * g1.w + b1.w;
  float4* op = (float4*)(outf + (size_t)row * DD);
  op[lane] = make_float4(r[0], r[1], r[2], r[3]);
  op[64 + lane] = make_float4(r[4], r[5], r[6], r[7]);
  ushort4 q0, q1;
  q0.x = f2b(r[0]); q0.y = f2b(r[1]); q0.z = f2b(r[2]); q0.w = f2b(r[3]);
  q1.x = f2b(r[4]); q1.y = f2b(r[5]); q1.z = f2b(r[6]); q1.w = f2b(r[7]);
  ushort4* ob = (ushort4*)(outb + (size_t)row * DD);
  ob[lane] = q0; ob[64 + lane] = q1;
}

// h = LN1(t + xin)*g1 + b1 + h ; then xinb = bf16(LN2(h)*g2 + b2)
__global__ __launch_bounds__(256) void resid_ln2(const float* __restrict__ t,
                                                 const float* __restrict__ xin,
                                                 float* __restrict__ h,
                                                 const float* __restrict__ g1,
                                                 const float* __restrict__ b1,
                                                 const float* __restrict__ g2,
                                                 const float* __restrict__ b2,
                                                 unsigned short* __restrict__ xinb) {
  const int wave = threadIdx.x >> 6, lane = threadIdx.x & 63;
  const int row = blockIdx.x * 4 + wave;
  const float* tp = t + (size_t)row * DD;
  const float* xp = xin + (size_t)row * DD;
  float4 t0 = ((const float4*)tp)[lane], t1 = ((const float4*)tp)[64 + lane];
  float4 x0 = ((const float4*)xp)[lane], x1 = ((const float4*)xp)[64 + lane];
  float v[8] = {t0.x + x0.x, t0.y + x0.y, t0.z + x0.z, t0.w + x0.w,
                t1.x + x1.x, t1.y + x1.y, t1.z + x1.z, t1.w + x1.w};
  float s = 0.f;
#pragma unroll
  for (int i = 0; i < 8; ++i) s += v[i];
  const float m = wsum(s) * (1.0f / 512.0f);
  float sq = 0.f;
#pragma unroll
  for (int i = 0; i < 8; ++i) { float d = v[i] - m; sq = fmaf(d, d, sq); }
  const float rs = rsqrtf(wsum(sq) * (1.0f / 512.0f) + 1e-5f);
  float4 g0 = ((const float4*)g1)[lane], g1v = ((const float4*)g1)[64 + lane];
  float4 c0 = ((const float4*)b1)[lane], c1 = ((const float4*)b1)[64 + lane];
  float4* hp = (float4*)(h + (size_t)row * DD);
  float4 h0 = hp[lane], h1 = hp[64 + lane];
  float a[8];
  a[0] = h0.x + (v[0] - m) * rs * g0.x + c0.x;  a[1] = h0.y + (v[1] - m) * rs * g0.y + c0.y;
  a[2] = h0.z + (v[2] - m) * rs * g0.z + c0.z;  a[3] = h0.w + (v[3] - m) * rs * g0.w + c0.w;
  a[4] = h1.x + (v[4] - m) * rs * g1v.x + c1.x; a[5] = h1.y + (v[5] - m) * rs * g1v.y + c1.y;
  a[6] = h1.z + (v[6] - m) * rs * g1v.z + c1.z; a[7] = h1.w + (v[7] - m) * rs * g1v.w + c1.w;
  hp[lane] = make_float4(a[0], a[1], a[2], a[3]);
  hp[64 + lane] = make_float4(a[4], a[5], a[6], a[7]);
  // second LN
  float s2 = 0.f;
#pragma unroll
  for (int i = 0; i < 8; ++i) s2 += a[i];
  const float m2 = wsum(s2) * (1.0f / 512.0f);
  float sq2 = 0.f;
#pragma unroll
  for (int i = 0; i < 8; ++i) { float d = a[i] - m2; sq2 = fmaf(d, d, sq2); }
  const float rs2 = rsqrtf(wsum(sq2) * (1.0f / 512.0f) + 1e-5f);
  float4 G0 = ((const float4*)g2)[lane], G1 = ((const float4*)g2)[64 + lane];
  float4 B0 = ((const float4*)b2)[lane], B1 = ((const float4*)b2)[64 + lane];
  ushort4 q0, q1;
  q0.x = f2b((a[0] - m2) * rs2 * G0.x + B0.x); q0.y = f2b((a[1] - m2) * rs2 * G0.y + B0.y);
  q0.z = f2b((a[2] - m2) * rs2 * G0.z + B0.z); q0.w = f2b((a[3] - m2) * rs2 * G0.w + B0.w);
  q1.x = f2b((a[4] - m2) * rs2 * G1.x + B1.x); q1.y = f2b((a[5] - m2) * rs2 * G1.y + B1.y);
  q1.z = f2b((a[6] - m2) * rs2 * G1.z + B1.z); q1.w = f2b((a[7] - m2) * rs2 * G1.w + B1.w);
  ushort4* ob = (ushort4*)(xinb + (size_t)row * DD);
  ob[lane] = q0; ob[64 + lane] = q1;
}

// ---------------- generic bf16 MFMA GEMM: C = A[M,K] @ Bt[N,K]^T ----------------
template<int BM, int BN, int WM, int WN, int EPI>
__global__ __launch_bounds__(256) void mgemm(const unsigned short* __restrict__ A,
                                             const unsigned short* __restrict__ Bt,
                                             void* __restrict__ C0, void* __restrict__ C1,
                                             void* __restrict__ C2,
                                             const float* __restrict__ bias,
                                             int M, int N, int K) {
  constexpr int NW = (BM / WM) * (BN / WN);
  constexpr int FM = WM / 16, FN = WN / 16;
  __shared__ char smem[(BM + BN) * 128];
  char* sA = smem; char* sB = smem + BM * 128;
  const int tid = threadIdx.x, lane = tid & 63, wid = tid >> 6;
  const int row0 = blockIdx.y * BM, col0 = blockIdx.x * BN;
  const int wrow = (wid / (BN / WN)) * WM, wcol = (wid % (BN / WN)) * WN;
  f32x4 acc[FM][FN] = {};
  const char* Ag = (const char*)(A + (size_t)row0 * K);
  const char* Bg = (const char*)(Bt + (size_t)col0 * K);
  for (int k0 = 0; k0 < K; k0 += 64) {
    __syncthreads();
    stage_rows(sA, Ag + (size_t)k0 * 2, (size_t)K * 2, BM / 8, wid, NW, lane);
    stage_rows(sB, Bg + (size_t)k0 * 2, (size_t)K * 2, BN / 8, wid, NW, lane);
    __syncthreads();
#pragma unroll
    for (int kk = 0; kk < 2; ++kk) {
      bf16x8 af[FM], bfr[FN];
#pragma unroll
      for (int mi = 0; mi < FM; ++mi)
        af[mi] = frag_ld(sA, wrow + mi * 16 + (lane & 15), kk * 4 + (lane >> 4));
#pragma unroll
      for (int ni = 0; ni < FN; ++ni)
        bfr[ni] = frag_ld(sB, wcol + ni * 16 + (lane & 15), kk * 4 + (lane >> 4));
#pragma unroll
      for (int mi = 0; mi < FM; ++mi)
#pragma unroll
        for (int ni = 0; ni < FN; ++ni)
          acc[mi][ni] = __builtin_amdgcn_mfma_f32_16x16x32_bf16(af[mi], bfr[ni], acc[mi][ni], 0, 0, 0);
    }
  }
#pragma unroll
  for (int mi = 0; mi < FM; ++mi)
#pragma unroll
    for (int ni = 0; ni < FN; ++ni) {
      const int colb = col0 + wcol + ni * 16;
      const int col = colb + (lane & 15);
      const int rowb = row0 + wrow + mi * 16 + (lane >> 4) * 4;
      if (EPI == 1 && (colb >> 9) == 2) {      // V segment -> vt[bh][d][t]
        const int cc = col - 1024, hh = cc >> 6, d = cc & 63, b = rowb >> 9, t = rowb & 511;
        ushort4 pk;
        pk.x = f2b(acc[mi][ni][0]); pk.y = f2b(acc[mi][ni][1]);
        pk.z = f2b(acc[mi][ni][2]); pk.w = f2b(acc[mi][ni][3]);
        *(ushort4*)((unsigned short*)C2 + (((size_t)(b * 8 + hh) * 64 + d) << 9) + t) = pk;
      } else {
#pragma unroll
        for (int r = 0; r < 4; ++r) {
          const int row = rowb + r;
          const float v = acc[mi][ni][r];
          if (EPI == 0) {
            ((float*)C0)[(size_t)row * N + col] = v;
          } else if (EPI == 1) {
            if (colb < 512) ((unsigned short*)C0)[(size_t)row * 512 + col] = f2b(v);
            else            ((unsigned short*)C1)[(size_t)row * 512 + (col - 512)] = f2b(v);
          } else if (EPI == 2) {
            ((unsigned short*)C0)[(size_t)row * N + col] = f2b(gelu_f(v + bias[col]));
          } else {
            ((float*)C0)[(size_t)row * N + col] += v + bias[col];
          }
        }
      }
    }
}

// ---------------- fused attention: S=QK^T -> entmax15 -> P@V, one wave = 16 q-rows ----
// grid (TC/64, B*H); block 256 = 4 waves. K staged in LDS once per block; the same
// 64KB buffer is re-staged with V during entmax (async load hidden under VALU work).
// XCD-swizzled block remap: all 8 q-tiles of one (b,h) land on one XCD's L2.
// All acc[] loops FULLY unrolled (rule #20).
__global__ __launch_bounds__(256, 2) void attn_fused(const unsigned short* __restrict__ q,
                                                     const unsigned short* __restrict__ k,
                                                     const unsigned short* __restrict__ vt,
                                                     const float* __restrict__ padf,
                                                     unsigned short* __restrict__ attnout) {
  __shared__ char sKV[65536];
  __shared__ char sP[4][2048];
  // bijective XCD remap (assumes RR dispatch linear%8 -> xcd; wrong assumption = perf-only)
  const int linear = blockIdx.x + 8 * blockIdx.y;          // 0..511
  const int idx = linear >> 3;                              // 0..63
  const int bh = (linear & 7) + 8 * (idx >> 3);             // 0..63, fixed xcd per bh
  const int qtile = idx & 7;                                // 0..7
  const int b = bh >> 3, hh = bh & 7;
  const int wid = threadIdx.x >> 6, lane = threadIdx.x & 63;
  const int q0 = qtile * 64 + wid * 16;
  const int col16 = lane & 15, g4 = lane >> 4;
  const unsigned short* qb = q + ((size_t)(b * TC + q0)) * DD + hh * HD;
  const unsigned short* kb = k + ((size_t)(b * TC)) * DD + hh * HD;
  const unsigned short* vb = vt + ((size_t)bh * 64) * 512;

  // ---- stage K slice [512 tok][64 d] (128B rows, stride 1024B) into LDS ----
  stage_rows(sKV, (const char*)kb, 1024, 64, wid, 4, lane);
  const unsigned short* qrow = qb + (size_t)col16 * DD + g4 * 8;
  bf16x8 aq0 = *(const bf16x8*)(qrow);
  bf16x8 aq1 = *(const bf16x8*)(qrow + 32);
  __syncthreads();   // drains vmcnt -> K resident

  // ---- S = Q K^T : 64 MFMA from LDS ----
  f32x4 acc[32] = {};
#pragma unroll
  for (int ni = 0; ni < 32; ++ni) {
    const int krow = 16 * ni + col16;
    bf16x8 b0 = frag_ld(sKV, krow, g4);
    bf16x8 b1 = frag_ld(sKV, krow, 4 + g4);
    acc[ni] = __builtin_amdgcn_mfma_f32_16x16x32_bf16(aq0, b0, acc[ni], 0, 0, 0);
    acc[ni] = __builtin_amdgcn_mfma_f32_16x16x32_bf16(aq1, b1, acc[ni], 0, 0, 0);
  }
  __syncthreads();   // all waves done reading K from LDS

  // ---- stage V slice (64KB linear) into the same buffer; entmax runs under it ----
  stage_rows_v(sKV, (const char*)vb, 64, wid, 4, lane);

  // ---- scale (/8 /2), key-pad mask, row max (UNSHIFTED; tau is absolute) ----
  const int btc = b * TC;
  float mx[4] = {-3.4e38f, -3.4e38f, -3.4e38f, -3.4e38f};
#pragma unroll
  for (int ni = 0; ni < 32; ++ni) {
    const float ma = padf[btc + 16 * ni + col16];
#pragma unroll
    for (int r = 0; r < 4; ++r) {
      acc[ni][r] = fmaf(acc[ni][r], 0.0625f, ma);
      mx[r] = fmaxf(mx[r], acc[ni][r]);
    }
  }
#pragma unroll
  for (int r = 0; r < 4; ++r) {
#pragma unroll
    for (int m = 1; m <= 8; m <<= 1) mx[r] = fmaxf(mx[r], __shfl_xor(mx[r], m, 64));
  }

  // ---- entmax15 tau: 3 support-iterations of the closed form.
  // tau0 = mx-1 <= tau*, so support is a superset that shrinks monotonically to S*.
  float tau[4] = {mx[0] - 1.f, mx[1] - 1.f, mx[2] - 1.f, mx[3] - 1.f};
  for (int it = 0; it < 3; ++it) {
    float c1[4] = {0, 0, 0, 0}, s1[4] = {0, 0, 0, 0}, s2[4] = {0, 0, 0, 0};
#pragma unroll
    for (int ni = 0; ni < 32; ++ni)
#pragma unroll
      for (int r = 0; r < 4; ++r) {
        const float vv = acc[ni][r];
        const float msk = (vv > tau[r]) ? 1.0f : 0.0f;
        c1[r] += msk; s1[r] += msk * vv; s2[r] = fmaf(msk * vv, vv, s2[r]);
      }
#pragma unroll
    for (int r = 0; r < 4; ++r) {
#pragma unroll
      for (int m = 1; m <= 8; m <<= 1) {
        c1[r] += __shfl_xor(c1[r], m, 64);
        s1[r] += __shfl_xor(s1[r], m, 64);
        s2[r] += __shfl_xor(s2[r], m, 64);
      }
      const float disc = fmaxf(s1[r] * s1[r] - c1[r] * s2[r] + c1[r], 0.f);
      tau[r] = (s1[r] - sqrtf(disc)) / c1[r];
    }
  }
  // ---- p = relu(v-tau)^2, renorm (bounds residual from any unconverged support) ----
  float inv[4];
  {
    float ss[4] = {0, 0, 0, 0};
#pragma unroll
    for (int ni = 0; ni < 32; ++ni)
#pragma unroll
      for (int r = 0; r < 4; ++r) {
        const float d = fmaxf(acc[ni][r] - tau[r], 0.f);
        acc[ni][r] = d * d;
        ss[r] = fmaf(d, d, ss[r]);
      }
#pragma unroll
    for (int r = 0; r < 4; ++r) {
#pragma unroll
      for (int m = 1; m <= 8; m <<= 1) ss[r] += __shfl_xor(ss[r], m, 64);
      inv[r] = 1.0f / ss[r];
    }
  }
  __syncthreads();   // drains vmcnt -> V resident in sKV

  // ---- P@V: per 64-key chunk, write P (bf16, swizzled) to wave-private LDS, MFMA ----
  char* myP = sP[wid];
  f32x4 acc2[4] = {};
#pragma unroll
  for (int c = 0; c < 8; ++c) {
#pragma unroll
    for (int nj = 0; nj < 4; ++nj) {
      const int ni = 4 * c + nj;
#pragma unroll
      for (int r = 0; r < 4; ++r) {
        const int lq = g4 * 4 + r;
        const int ck = nj * 16 + col16;
        *(unsigned short*)(myP + lq * 128 + ((((ck >> 3) ^ (lq & 7))) << 4) + ((ck & 7) << 1)) =
            f2b(acc[ni][r] * inv[r]);
      }
    }
#pragma unroll
    for (int kk = 0; kk < 2; ++kk) {
      const bf16x8 pa = frag_ld(myP, col16, kk * 4 + g4);
#pragma unroll
      for (int n2 = 0; n2 < 4; ++n2) {
        // V fragment: d-row (16*n2+col16), key cols c*64+kk*32+g4*8 -> 128B-row d*8+c
        const bf16x8 vv = frag_ld_v(sKV, (16 * n2 + col16) * 8 + c, kk * 4 + g4);
        acc2[n2] = __builtin_amdgcn_mfma_f32_16x16x32_bf16(pa, vv, acc2[n2], 0, 0, 0);
      }
    }
  }
#pragma unroll
  for (int n2 = 0; n2 < 4; ++n2)
#pragma unroll
    for (int r = 0; r < 4; ++r)
      attnout[((size_t)(b * TC + q0 + g4 * 4 + r)) * DD + hh * HD + 16 * n2 + col16] = f2b(acc2[n2][r]);
}

// ---------------- head ----------------
__global__ void head_k(const float* __restrict__ h, const float* __restrict__ w1,
                       const float* __restrict__ b1, const float* __restrict__ w2,
                       const float* __restrict__ b2, float* __restrict__ out) {
  __shared__ float z[BB][HEADH];
  const int tid = threadIdx.x;
  const int b = tid >> 5, j = tid & 31;
  const float* hr = h + (size_t)(b * TC) * DD;
  float s = 0.f;
  for (int kk = 0; kk < DD; ++kk) s = fmaf(hr[kk], w1[kk * HEADH + j], s);
  z[b][j] = fmaxf(s + b1[j], 0.f);
  __syncthreads();
  if (tid < BB) {
    float acc = b2[0];
#pragma unroll
    for (int q2 = 0; q2 < HEADH; ++q2) acc = fmaf(z[tid][q2], w2[q2], acc);
    out[tid] = acc;
  }
}

// ---------------- workspace layout ----------------
#define WS_NEED 58736640ull
static __device__ __align__(256) unsigned char g_fallback_ws[WS_NEED];

extern "C" void kernel_launch(void* const* d_in, const int* in_sizes, int n_in,
                              void* d_out, int out_size, void* d_ws, size_t ws_size,
                              hipStream_t stream) {
  const int*   x     = (const int*)d_in[0];
  const float* etab  = (const float*)d_in[1];
  const float* ptab  = (const float*)d_in[2];
  const float* cls   = (const float*)d_in[3];
  const float* Wq    = (const float*)d_in[4];
  const float* Wk    = (const float*)d_in[5];
  const float* Wv    = (const float*)d_in[6];
  const float* Wo    = (const float*)d_in[7];
  const float* an_g  = (const float*)d_in[8];
  const float* an_b  = (const float*)d_in[9];
  const float* ln1_g = (const float*)d_in[10];
  const float* ln1_b = (const float*)d_in[11];
  const float* ln2_g = (const float*)d_in[12];
  const float* ln2_b = (const float*)d_in[13];
  const float* f1_w  = (const float*)d_in[14];
  const float* f1_b  = (const float*)d_in[15];
  const float* f2_w  = (const float*)d_in[16];
  const float* f2_b  = (const float*)d_in[17];
  const float* h1_w  = (const float*)d_in[18];
  const float* h1_b  = (const float*)d_in[19];
  const float* h2_w  = (const float*)d_in[20];
  const float* h2_b  = (const float*)d_in[21];
  float* out = (float*)d_out;

  void* wsbase = d_ws;
  if (ws_size < WS_NEED) hipGetSymbolAddress(&wsbase, HIP_SYMBOL(g_fallback_ws));
  char* base = (char*)wsbase;
  const size_t MB = 1048576;
  float* h_    = (float*)(base);
  float* xin_  = (float*)(base + 8 * MB);
  float* t_    = (float*)(base + 16 * MB);
  unsigned short* xinb_ = (unsigned short*)(base + 24 * MB);
  unsigned short* q_    = (unsigned short*)(base + 28 * MB);
  unsigned short* k_    = (unsigned short*)(base + 32 * MB);
  unsigned short* vt_   = (unsigned short*)(base + 36 * MB);
  unsigned short* at_   = (unsigned short*)(base + 40 * MB);
  unsigned short* mid_  = (unsigned short*)(base + 44 * MB);
  unsigned short* qkvT_ = (unsigned short*)(base + 46 * MB);
  unsigned short* woT_  = (unsigned short*)(base + 52 * MB);
  unsigned short* f1T_  = (unsigned short*)(base + 54 * MB);
  unsigned short* f2T_  = (unsigned short*)(base + 55 * MB);
  float* padf_ = (float*)(base + 56 * MB);

  wprep<<<dim3(16, 16, 24), 256, 0, stream>>>(Wq, Wk, Wv, Wo, f1_w, f2_w, qkvT_, woT_, f1T_, f2T_);
  embed_k<<<NTOK, 64, 0, stream>>>(x, etab, ptab, cls, h_, padf_);

  for (int l = 0; l < LL; ++l) {
    ln_rows<<<NTOK / 4, 256, 0, stream>>>(h_, xin_, xinb_, ln1_g + l * DD, ln1_b + l * DD);
    mgemm<128, 128, 64, 64, 1><<<dim3(12, 32), 256, 0, stream>>>(
        xinb_, qkvT_ + (size_t)l * 1536 * 512, q_, k_, vt_, nullptr, NTOK, 1536, 512);
    attn_fused<<<dim3(TC / 64, BB * HH), 256, 0, stream>>>(q_, k_, vt_, padf_, at_);
    mgemm<128, 128, 64, 64, 0><<<dim3(4, 32), 256, 0, stream>>>(
        at_, woT_ + (size_t)l * 512 * 512, t_, nullptr, nullptr, nullptr, NTOK, 512, 512);
    resid_ln2<<<NTOK / 4, 256, 0, stream>>>(t_, xin_, h_, an_g + l * DD, an_b + l * DD,
                                            ln2_g + l * DD, ln2_b + l * DD, xinb_);
    mgemm<64, 64, 32, 32, 2><<<dim3(4, 64), 256, 0, stream>>>(
        xinb_, f1T_ + (size_t)l * 256 * 512, mid_, nullptr, nullptr, f1_b + l * FF, NTOK, 256, 512);
    mgemm<64, 128, 32, 64, 3><<<dim3(4, 64), 256, 0, stream>>>(
        mid_, f2T_ + (size_t)l * 512 * 256, h_, nullptr, nullptr, f2_b + l * DD, NTOK, 512, 256);
  }

  head_k<<<1, 256, 0, stream>>>(h_, h1_w, h1_b, h2_w, h2_b, out);
}